// Round 6
// baseline (785.963 us; speedup 1.0000x reference)
//
#include <hip/hip_runtime.h>
#include <stdint.h>

// ---------------------------------------------------------------------------
// Fused wavelet window-attention, register-resident y / per-lane softmax.
//   Block = 512 thr: one (unit, quarter) = 4 orig rows x 64 orig cols.
//   bands[4][c64][px64+2pad] f16 (33792B): DWT out, conflict-free u32 writes.
//   qk (32KB): granule(G,npair,wl) = 16B holding {n&1, q(4 spatial)} f16.
//     low/high: Q G0..15, K 16..31, V 32..47.  mid: Q 0..31, K-half 32..47,
//     V-half 48..63 (two d-passes, online accumulation, no max needed).
//   Thread owns (window W, ch pair A,A+1) consistent across paths; y in regs;
//   iDWT per-thread; direct float4 stores.
// ---------------------------------------------------------------------------

typedef _Float16 halfT;
typedef __attribute__((ext_vector_type(2))) _Float16 half2T;
typedef __attribute__((ext_vector_type(8))) _Float16 half8;
typedef __attribute__((ext_vector_type(4))) float f32x4;

union H8 { half8 v; half2T h2[4]; uint16_t s[8]; };

static __device__ __forceinline__ uint16_t f2h(float f){
  union { halfT h; uint16_t u; } x; x.h = (halfT)f; return x.u;
}
static __device__ __forceinline__ float dot4(half2T a0, half2T a1,
                                             half2T b0, half2T b1){
#if __has_builtin(__builtin_amdgcn_fdot2)
  return __builtin_amdgcn_fdot2(a1, b1, __builtin_amdgcn_fdot2(a0, b0, 0.f, false), false);
#else
  half2T p = a0*b0 + a1*b1;
  return (float)p.x + (float)p.y;
#endif
}

__global__ void k_wt(const float* __restrict__ wlh, const float* __restrict__ wm,
                     halfT* __restrict__ wH){
  int i = blockIdx.x * 256 + threadIdx.x;
  if (i < 12288)      wH[i] = (halfT)wlh[i];
  else if (i < 61440) wH[i] = (halfT)wm[i - 12288];
}

#define BSTR  66
#define BSLAB 4224

static __device__ __forceinline__ int qidx(int G, int npair, int wl){
  return G*256 + npair*128 + ((wl ^ (G & 7)) << 3);
}

__global__ __launch_bounds__(512, 4) void k_fused(const float* __restrict__ x,
    const halfT* __restrict__ wH, float* __restrict__ out){
  __shared__ __align__(16) uint16_t bands[4*BSLAB];  // 33792 B
  __shared__ __align__(16) uint16_t qk[16384];       // 32768 B

  const int tid = threadIdx.x;
  const int wv = tid >> 6, lane = tid & 63;
  const int unit = blockIdx.x >> 2, q4 = blockIdx.x & 3;
  const int b = unit >> 6, hw = unit & 63;
  const int col0 = q4 * 64;
  const float* xb = x + (size_t)b * 64 * 65536;
  const halfT* wM = wH + 12288;

  // ---------------- phase A: load x + Haar DWT -> bands[c][px] ------------
  #pragma unroll
  for (int it = 0; it < 4; ++it){
    int idx = it*512 + tid;
    int j = idx & 15, rp = (idx >> 4) & 1, c = idx >> 5;
    const float* src = xb + (size_t)c*65536 + (size_t)(4*hw + 2*rp)*256 + col0 + 4*j;
    float4 r0 = *(const float4*)src;
    float4 r1 = *(const float4*)(src + 256);
    float v0[4], v1[4];
    v0[0] = 0.5f*( r0.x + r0.y + r1.x + r1.y);
    v0[1] = 0.5f*(-r0.x - r0.y + r1.x + r1.y);
    v0[2] = 0.5f*(-r0.x + r0.y - r1.x + r1.y);
    v0[3] = 0.5f*( r0.x - r0.y - r1.x + r1.y);
    v1[0] = 0.5f*( r0.z + r0.w + r1.z + r1.w);
    v1[1] = 0.5f*(-r0.z - r0.w + r1.z + r1.w);
    v1[2] = 0.5f*(-r0.z + r0.w - r1.z + r1.w);
    v1[3] = 0.5f*( r0.z - r0.w - r1.z + r1.w);
    int base = c*BSTR + rp*32 + 2*j;
    #pragma unroll
    for (int bb = 0; bb < 4; ++bb)
      *(uint32_t*)&bands[bb*BSLAB + base] =
          (uint32_t)f2h(v0[bb]) | ((uint32_t)f2h(v1[bb]) << 16);
  }
  __syncthreads();

  const int mrow = lane & 15, g = lane >> 4;
  const int m = lane & 31;
  const int W = wv*2 + (lane >> 5);   // window 0..15, fixed per thread
  const int A = 2*m;                  // ch pair base, fixed per thread
  const int np = m & 1;               // npair for rows A, A+1
  const int pxb = (wv & 3)*16 + mrow; // conv N-column (this wave)
  const int wl = (pxb & 31) >> 1, qq = (pxb >> 5)*2 + (pxb & 1);
  const int ms = wv >> 2;

  float y0[2][4], y1[2][4], y2[2][4], y3[2][4];

  // ======================= LOW path (band 0, y0) ==========================
  {
    half8 bfr[2];
    #pragma unroll
    for (int ks = 0; ks < 2; ++ks){
      H8 t; int cb = ks*32 + g*8;
      #pragma unroll
      for (int k = 0; k < 8; ++k) t.s[k] = bands[0*BSLAB + (cb + k)*BSTR + pxb];
      bfr[ks] = t.v;
    }
    #pragma unroll
    for (int mi = 0; mi < 6; ++mi){
      int mt = ms*6 + mi;
      f32x4 acc = {0.f,0.f,0.f,0.f};
      #pragma unroll
      for (int ks = 0; ks < 2; ++ks){
        half8 a = *(const half8*)&wH[(mt*16 + mrow)*64 + ks*32 + g*8];
        acc = __builtin_amdgcn_mfma_f32_16x16x32_f16(a, bfr[ks], acc, 0, 0, 0);
      }
      #pragma unroll
      for (int r = 0; r < 4; ++r){
        int tl = mt*16 + g*4 + r;
        int G = tl >> 2, n = tl & 3;
        qk[qidx(G, n>>1, wl) + (n&1)*4 + qq] = f2h(acc[r]);
      }
    }
  }
  __syncthreads();
  {
    const halfT sh = (halfT)0.25f;
    const half8 s8 = {sh,sh,sh,sh,sh,sh,sh,sh};
    H8 qg; qg.v = *(const half8*)&qk[qidx(m>>1, np, W)];
    qg.v = qg.v * s8;
    float sum0=0.f, sum1=0.f, po0[4]={0,0,0,0}, po1[4]={0,0,0,0};
    #pragma unroll
    for (int d = 0; d < 16; ++d){
      H8 kg, vg;
      kg.v = *(const half8*)&qk[qidx(16+d, np, W)];
      vg.v = *(const half8*)&qk[qidx(32+d, np, W)];
      float a0 = dot4(qg.h2[0], qg.h2[1], kg.h2[0], kg.h2[1]);
      float a1 = dot4(qg.h2[2], qg.h2[3], kg.h2[2], kg.h2[3]);
      float e0 = __expf(a0), e1 = __expf(a1);
      sum0 += e0; sum1 += e1;
      #pragma unroll
      for (int s2 = 0; s2 < 4; ++s2){
        po0[s2] += e0 * (float)vg.v[s2];
        po1[s2] += e1 * (float)vg.v[4+s2];
      }
    }
    float i0 = __builtin_amdgcn_rcpf(sum0), i1 = __builtin_amdgcn_rcpf(sum1);
    #pragma unroll
    for (int s2 = 0; s2 < 4; ++s2){ y0[0][s2] = po0[s2]*i0; y0[1][s2] = po1[s2]*i1; }
  }
  __syncthreads();

  // ======================= MID path (bands 1,2 -> y1,y2) ==================
  {
    float sum[4] = {0,0,0,0};
    float po[4][4] = {{0,0,0,0},{0,0,0,0},{0,0,0,0},{0,0,0,0}};
    H8 qa, qb;
    const halfT shm = (halfT)0.17677669529663687f;
    const half8 s8m = {shm,shm,shm,shm,shm,shm,shm,shm};
    #pragma unroll
    for (int p = 0; p < 2; ++p){
      { // conv pass p: p0 -> Q + K[d<16] + V[d<16]; p1 -> K[d>=16] + V[d>=16]
        half8 bfr[4];
        #pragma unroll
        for (int ks = 0; ks < 4; ++ks){
          H8 t; int band = 1 + (ks >> 1); int cb = (ks & 1)*32 + g*8;
          #pragma unroll
          for (int k = 0; k < 8; ++k) t.s[k] = bands[band*BSLAB + (cb + k)*BSTR + pxb];
          bfr[ks] = t.v;
        }
        const int nmt = p ? 4 : 8;
        #pragma unroll
        for (int mi = 0; mi < 8; ++mi){
          if (mi >= nmt) break;
          int mt;
          if (p == 0){ int i2 = ms*8 + mi; mt = (i2 < 12) ? i2 : i2 + 4; }
          else       { int i2 = ms*4 + mi; mt = (i2 < 4) ? 12 + i2 : 16 + i2; }
          f32x4 acc = {0.f,0.f,0.f,0.f};
          #pragma unroll
          for (int ks = 0; ks < 4; ++ks){
            half8 a = *(const half8*)&wM[(mt*16 + mrow)*128 + ks*32 + g*8];
            acc = __builtin_amdgcn_mfma_f32_16x16x32_f16(a, bfr[ks], acc, 0, 0, 0);
          }
          int goff = (mt < 12) ? 0 : ((mt < 20) ? 16 : 32);
          #pragma unroll
          for (int r = 0; r < 4; ++r){
            int tl = mt*16 + g*4 + r;
            int G = (tl >> 2) - goff, n = tl & 3;
            qk[qidx(G, n>>1, wl) + (n&1)*4 + qq] = f2h(acc[r]);
          }
        }
      }
      __syncthreads();
      if (p == 0){
        qa.v = *(const half8*)&qk[qidx(m>>1, np, W)];        qa.v = qa.v * s8m;
        qb.v = *(const half8*)&qk[qidx((m>>1)+16, np, W)];   qb.v = qb.v * s8m;
      }
      #pragma unroll
      for (int dl = 0; dl < 16; ++dl){
        H8 kg, vg;
        kg.v = *(const half8*)&qk[qidx(32+dl, np, W)];
        vg.v = *(const half8*)&qk[qidx(48+dl, np, W)];
        float a0 = dot4(qa.h2[0], qa.h2[1], kg.h2[0], kg.h2[1]);
        float a1 = dot4(qa.h2[2], qa.h2[3], kg.h2[2], kg.h2[3]);
        float a2 = dot4(qb.h2[0], qb.h2[1], kg.h2[0], kg.h2[1]);
        float a3 = dot4(qb.h2[2], qb.h2[3], kg.h2[2], kg.h2[3]);
        float e0 = __expf(a0), e1 = __expf(a1);
        float e2 = __expf(a2), e3 = __expf(a3);
        sum[0] += e0; sum[1] += e1; sum[2] += e2; sum[3] += e3;
        #pragma unroll
        for (int s2 = 0; s2 < 4; ++s2){
          float vlo = (float)vg.v[s2], vhi = (float)vg.v[4+s2];
          po[0][s2] += e0*vlo; po[1][s2] += e1*vhi;
          po[2][s2] += e2*vlo; po[3][s2] += e3*vhi;
        }
      }
      __syncthreads();
    }
    float i0 = __builtin_amdgcn_rcpf(sum[0]), i1 = __builtin_amdgcn_rcpf(sum[1]);
    float i2 = __builtin_amdgcn_rcpf(sum[2]), i3 = __builtin_amdgcn_rcpf(sum[3]);
    #pragma unroll
    for (int s2 = 0; s2 < 4; ++s2){
      y1[0][s2] = po[0][s2]*i0; y1[1][s2] = po[1][s2]*i1;
      y2[0][s2] = po[2][s2]*i2; y2[1][s2] = po[3][s2]*i3;
    }
  }

  // ======================= HIGH path (band 3, y3) =========================
  {
    half8 bfr[2];
    #pragma unroll
    for (int ks = 0; ks < 2; ++ks){
      H8 t; int cb = ks*32 + g*8;
      #pragma unroll
      for (int k = 0; k < 8; ++k) t.s[k] = bands[3*BSLAB + (cb + k)*BSTR + pxb];
      bfr[ks] = t.v;
    }
    #pragma unroll
    for (int mi = 0; mi < 6; ++mi){
      int mt = ms*6 + mi;
      f32x4 acc = {0.f,0.f,0.f,0.f};
      #pragma unroll
      for (int ks = 0; ks < 2; ++ks){
        half8 a = *(const half8*)&wH[(mt*16 + mrow)*64 + ks*32 + g*8];
        acc = __builtin_amdgcn_mfma_f32_16x16x32_f16(a, bfr[ks], acc, 0, 0, 0);
      }
      #pragma unroll
      for (int r = 0; r < 4; ++r){
        int tl = mt*16 + g*4 + r;
        int G = tl >> 2, n = tl & 3;
        qk[qidx(G, n>>1, wl) + (n&1)*4 + qq] = f2h(acc[r]);
      }
    }
  }
  __syncthreads();
  {
    const halfT sh = (halfT)0.25f;
    const half8 s8 = {sh,sh,sh,sh,sh,sh,sh,sh};
    H8 qg; qg.v = *(const half8*)&qk[qidx(m>>1, np, W)];
    qg.v = qg.v * s8;
    float sum0=0.f, sum1=0.f, po0[4]={0,0,0,0}, po1[4]={0,0,0,0};
    #pragma unroll
    for (int d = 0; d < 16; ++d){
      H8 kg, vg;
      kg.v = *(const half8*)&qk[qidx(16+d, np, W)];
      vg.v = *(const half8*)&qk[qidx(32+d, np, W)];
      float a0 = dot4(qg.h2[0], qg.h2[1], kg.h2[0], kg.h2[1]);
      float a1 = dot4(qg.h2[2], qg.h2[3], kg.h2[2], kg.h2[3]);
      float e0 = __expf(a0), e1 = __expf(a1);
      sum0 += e0; sum1 += e1;
      #pragma unroll
      for (int s2 = 0; s2 < 4; ++s2){
        po0[s2] += e0 * (float)vg.v[s2];
        po1[s2] += e1 * (float)vg.v[4+s2];
      }
    }
    float i0 = __builtin_amdgcn_rcpf(sum0), i1 = __builtin_amdgcn_rcpf(sum1);
    #pragma unroll
    for (int s2 = 0; s2 < 4; ++s2){ y3[0][s2] = po0[s2]*i0; y3[1][s2] = po1[s2]*i1; }
  }

  // ================= iDWT in registers + direct stores ====================
  #pragma unroll
  for (int chi = 0; chi < 2; ++chi){
    int ch = A + chi;
    float* dst = out + (((size_t)b*64 + ch)*256 + (size_t)(4*hw))*256 + col0 + 4*W;
    #pragma unroll
    for (int rp = 0; rp < 2; ++rp){
      float4 top, bot;
      #pragma unroll
      for (int cp = 0; cp < 2; ++cp){
        int s2 = rp*2 + cp;
        float ll = y0[chi][s2], lh = y1[chi][s2];
        float hl = y2[chi][s2], hh = y3[chi][s2];
        float va = 0.5f*(ll - lh - hl + hh);
        float vb = 0.5f*(ll - lh + hl - hh);
        float vc = 0.5f*(ll + lh - hl - hh);
        float vd = 0.5f*(ll + lh + hl + hh);
        if (cp == 0){ top.x = va; top.y = vb; bot.x = vc; bot.y = vd; }
        else        { top.z = va; top.w = vb; bot.z = vc; bot.w = vd; }
      }
      *(float4*)(dst + (size_t)(2*rp)*256)   = top;
      *(float4*)(dst + (size_t)(2*rp+1)*256) = bot;
    }
  }
}

// ---------------------------------------------------------------------------
extern "C" void kernel_launch(void* const* d_in, const int* in_sizes, int n_in,
                              void* d_out, int out_size, void* d_ws, size_t ws_size,
                              hipStream_t stream){
  const float* x   = (const float*)d_in[0];
  const float* wlh = (const float*)d_in[1];
  const float* wm  = (const float*)d_in[2];
  float* out = (float*)d_out;
  halfT* wH = (halfT*)d_ws;                // 61440 f16 = 122880 B

  hipLaunchKernelGGL(k_wt,    dim3(240),  dim3(256), 0, stream, wlh, wm, wH);
  hipLaunchKernelGGL(k_fused, dim3(2048), dim3(512), 0, stream, x, wH, out);
}

// Round 8
// 751.261 us; speedup vs baseline: 1.0462x; 1.0462x over previous
//
#include <hip/hip_runtime.h>
#include <stdint.h>

// ---------------------------------------------------------------------------
// Fused wavelet window-attention, register-resident y / per-lane softmax.
//   Block = 512 thr: one (unit, quarter) = 4 orig rows x 64 orig cols.
//   smem (70656B) = bands[4][c64][66] f16 (33792B) + qk (32KB); reused at the
//   end as ot[f32]: ch*276 + row*68 + granule(XOR-swz)*4 (all 16B-aligned).
//   qk granule(G,npair,wl) = 16B: channels {4G+2npair, +1} x q(4 spatial).
//   Thread owns (window W, ch pair A,A+1) across paths; y in regs; iDWT in
//   regs; LDS-staged coalesced float4 stores (full-line, no RMW).
// ---------------------------------------------------------------------------

typedef _Float16 halfT;
typedef __attribute__((ext_vector_type(2))) _Float16 half2T;
typedef __attribute__((ext_vector_type(8))) _Float16 half8;
typedef __attribute__((ext_vector_type(4))) float f32x4;

union H8 { half8 v; half2T h2[4]; uint16_t s[8]; };

static __device__ __forceinline__ uint16_t f2h(float f){
  union { halfT h; uint16_t u; } x; x.h = (halfT)f; return x.u;
}
static __device__ __forceinline__ float dot4(half2T a0, half2T a1,
                                             half2T b0, half2T b1){
#if __has_builtin(__builtin_amdgcn_fdot2)
  return __builtin_amdgcn_fdot2(a1, b1, __builtin_amdgcn_fdot2(a0, b0, 0.f, false), false);
#else
  half2T p = a0*b0 + a1*b1;
  return (float)p.x + (float)p.y;
#endif
}

__global__ void k_wt(const float* __restrict__ wlh, const float* __restrict__ wm,
                     halfT* __restrict__ wH){
  int i = blockIdx.x * 256 + threadIdx.x;
  if (i < 12288)      wH[i] = (halfT)wlh[i];
  else if (i < 61440) wH[i] = (halfT)wm[i - 12288];
}

#define BSTR  66
#define BSLAB 4224
#define OT_CS 276
#define OT_RS 68

static __device__ __forceinline__ int qidx(int G, int npair, int wl){
  return G*256 + npair*128 + ((wl ^ (G & 7)) << 3);
}

__global__ __launch_bounds__(512, 4) void k_fused(const float* __restrict__ x,
    const halfT* __restrict__ wH, float* __restrict__ out){
  __shared__ __align__(16) uint8_t smem[70656];
  uint16_t* bands = (uint16_t*)smem;                 // 33792 B
  uint16_t* qk    = (uint16_t*)(smem + 33792);       // 32768 B
  float*    ot    = (float*)smem;                    // reused at end

  const int tid = threadIdx.x;
  const int wv = tid >> 6, lane = tid & 63;
  const int unit = blockIdx.x >> 2, q4 = blockIdx.x & 3;
  const int b = unit >> 6, hw = unit & 63;
  const int col0 = q4 * 64;
  const float* xb = x + (size_t)b * 64 * 65536;
  const halfT* wM = wH + 12288;

  // ---------------- phase A: load x + Haar DWT -> bands[c][px] ------------
  #pragma unroll
  for (int it = 0; it < 4; ++it){
    int idx = it*512 + tid;
    int j = idx & 15, rp = (idx >> 4) & 1, c = idx >> 5;
    const float* src = xb + (size_t)c*65536 + (size_t)(4*hw + 2*rp)*256 + col0 + 4*j;
    float4 r0 = *(const float4*)src;
    float4 r1 = *(const float4*)(src + 256);
    float v0[4], v1[4];
    v0[0] = 0.5f*( r0.x + r0.y + r1.x + r1.y);
    v0[1] = 0.5f*(-r0.x - r0.y + r1.x + r1.y);
    v0[2] = 0.5f*(-r0.x + r0.y - r1.x + r1.y);
    v0[3] = 0.5f*( r0.x - r0.y - r1.x + r1.y);
    v1[0] = 0.5f*( r0.z + r0.w + r1.z + r1.w);
    v1[1] = 0.5f*(-r0.z - r0.w + r1.z + r1.w);
    v1[2] = 0.5f*(-r0.z + r0.w - r1.z + r1.w);
    v1[3] = 0.5f*( r0.z - r0.w - r1.z + r1.w);
    int base = c*BSTR + rp*32 + 2*j;
    #pragma unroll
    for (int bb = 0; bb < 4; ++bb)
      *(uint32_t*)&bands[bb*BSLAB + base] =
          (uint32_t)f2h(v0[bb]) | ((uint32_t)f2h(v1[bb]) << 16);
  }
  __syncthreads();

  const int mrow = lane & 15, g = lane >> 4;
  const int m = lane & 31;
  const int W = wv*2 + (lane >> 5);   // window 0..15, fixed per thread
  const int A = 2*m;                  // ch pair base, fixed per thread
  const int np = m & 1;               // npair for rows A, A+1
  const int pxb = (wv & 3)*16 + mrow; // conv N-column (this wave)
  const int wl = (pxb & 31) >> 1, qq = (pxb >> 5)*2 + (pxb & 1);
  const int ms = wv >> 2;

  float y0[2][4], y1[2][4], y2[2][4], y3[2][4];

  // ======================= LOW path (band 0, y0) ==========================
  {
    half8 bfr[2];
    #pragma unroll
    for (int ks = 0; ks < 2; ++ks){
      H8 t; int cb = ks*32 + g*8;
      #pragma unroll
      for (int k = 0; k < 8; ++k) t.s[k] = bands[0*BSLAB + (cb + k)*BSTR + pxb];
      bfr[ks] = t.v;
    }
    #pragma unroll
    for (int mi = 0; mi < 6; ++mi){
      int mt = ms*6 + mi;
      f32x4 acc = {0.f,0.f,0.f,0.f};
      #pragma unroll
      for (int ks = 0; ks < 2; ++ks){
        half8 a = *(const half8*)&wH[(mt*16 + mrow)*64 + ks*32 + g*8];
        acc = __builtin_amdgcn_mfma_f32_16x16x32_f16(a, bfr[ks], acc, 0, 0, 0);
      }
      #pragma unroll
      for (int r = 0; r < 4; ++r){
        int tl = mt*16 + g*4 + r;
        int G = tl >> 2, n = tl & 3;
        qk[qidx(G, n>>1, wl) + (n&1)*4 + qq] = f2h(acc[r]);
      }
    }
  }
  __syncthreads();
  {
    const halfT sh = (halfT)0.25f;
    const half8 s8 = {sh,sh,sh,sh,sh,sh,sh,sh};
    H8 qg; qg.v = *(const half8*)&qk[qidx(m>>1, np, W)];
    qg.v = qg.v * s8;
    float sum0=0.f, sum1=0.f, po0[4]={0,0,0,0}, po1[4]={0,0,0,0};
    #pragma unroll
    for (int d = 0; d < 16; ++d){
      H8 kg, vg;
      kg.v = *(const half8*)&qk[qidx(16+d, np, W)];
      vg.v = *(const half8*)&qk[qidx(32+d, np, W)];
      float a0 = dot4(qg.h2[0], qg.h2[1], kg.h2[0], kg.h2[1]);
      float a1 = dot4(qg.h2[2], qg.h2[3], kg.h2[2], kg.h2[3]);
      float e0 = __expf(a0), e1 = __expf(a1);
      sum0 += e0; sum1 += e1;
      #pragma unroll
      for (int s2 = 0; s2 < 4; ++s2){
        po0[s2] += e0 * (float)vg.v[s2];
        po1[s2] += e1 * (float)vg.v[4+s2];
      }
    }
    float i0 = __builtin_amdgcn_rcpf(sum0), i1 = __builtin_amdgcn_rcpf(sum1);
    #pragma unroll
    for (int s2 = 0; s2 < 4; ++s2){ y0[0][s2] = po0[s2]*i0; y0[1][s2] = po1[s2]*i1; }
  }
  __syncthreads();

  // ======================= MID path (bands 1,2 -> y1,y2) ==================
  {
    float sum[4] = {0,0,0,0};
    float po[4][4] = {{0,0,0,0},{0,0,0,0},{0,0,0,0},{0,0,0,0}};
    H8 qa, qb;
    const halfT shm = (halfT)0.17677669529663687f;
    const half8 s8m = {shm,shm,shm,shm,shm,shm,shm,shm};
    #pragma unroll
    for (int p = 0; p < 2; ++p){
      { // conv pass p: p0 -> Q + K[d<16] + V[d<16]; p1 -> K[d>=16] + V[d>=16]
        half8 bfr[4];
        #pragma unroll
        for (int ks = 0; ks < 4; ++ks){
          H8 t; int band = 1 + (ks >> 1); int cb = (ks & 1)*32 + g*8;
          #pragma unroll
          for (int k = 0; k < 8; ++k) t.s[k] = bands[band*BSLAB + (cb + k)*BSTR + pxb];
          bfr[ks] = t.v;
        }
        const int nmt = p ? 4 : 8;
        #pragma unroll
        for (int mi = 0; mi < 8; ++mi){
          if (mi >= nmt) break;
          int mt;
          if (p == 0){ int i2 = ms*8 + mi; mt = (i2 < 12) ? i2 : i2 + 4; }
          else       { int i2 = ms*4 + mi; mt = (i2 < 4) ? 12 + i2 : 16 + i2; }
          f32x4 acc = {0.f,0.f,0.f,0.f};
          #pragma unroll
          for (int ks = 0; ks < 4; ++ks){
            half8 a = *(const half8*)&wM[(mt*16 + mrow)*128 + ks*32 + g*8];
            acc = __builtin_amdgcn_mfma_f32_16x16x32_f16(a, bfr[ks], acc, 0, 0, 0);
          }
          int goff = (mt < 12) ? 0 : ((mt < 20) ? 16 : 32);
          #pragma unroll
          for (int r = 0; r < 4; ++r){
            int tl = mt*16 + g*4 + r;
            int G = (tl >> 2) - goff, n = tl & 3;
            qk[qidx(G, n>>1, wl) + (n&1)*4 + qq] = f2h(acc[r]);
          }
        }
      }
      __syncthreads();
      if (p == 0){
        qa.v = *(const half8*)&qk[qidx(m>>1, np, W)];        qa.v = qa.v * s8m;
        qb.v = *(const half8*)&qk[qidx((m>>1)+16, np, W)];   qb.v = qb.v * s8m;
      }
      #pragma unroll
      for (int dl = 0; dl < 16; ++dl){
        H8 kg, vg;
        kg.v = *(const half8*)&qk[qidx(32+dl, np, W)];
        vg.v = *(const half8*)&qk[qidx(48+dl, np, W)];
        float a0 = dot4(qa.h2[0], qa.h2[1], kg.h2[0], kg.h2[1]);
        float a1 = dot4(qa.h2[2], qa.h2[3], kg.h2[2], kg.h2[3]);
        float a2 = dot4(qb.h2[0], qb.h2[1], kg.h2[0], kg.h2[1]);
        float a3 = dot4(qb.h2[2], qb.h2[3], kg.h2[2], kg.h2[3]);
        float e0 = __expf(a0), e1 = __expf(a1);
        float e2 = __expf(a2), e3 = __expf(a3);
        sum[0] += e0; sum[1] += e1; sum[2] += e2; sum[3] += e3;
        #pragma unroll
        for (int s2 = 0; s2 < 4; ++s2){
          float vlo = (float)vg.v[s2], vhi = (float)vg.v[4+s2];
          po[0][s2] += e0*vlo; po[1][s2] += e1*vhi;
          po[2][s2] += e2*vlo; po[3][s2] += e3*vhi;
        }
      }
      __syncthreads();
    }
    float i0 = __builtin_amdgcn_rcpf(sum[0]), i1 = __builtin_amdgcn_rcpf(sum[1]);
    float i2 = __builtin_amdgcn_rcpf(sum[2]), i3 = __builtin_amdgcn_rcpf(sum[3]);
    #pragma unroll
    for (int s2 = 0; s2 < 4; ++s2){
      y1[0][s2] = po[0][s2]*i0; y1[1][s2] = po[1][s2]*i1;
      y2[0][s2] = po[2][s2]*i2; y2[1][s2] = po[3][s2]*i3;
    }
  }

  // ======================= HIGH path (band 3, y3) =========================
  {
    half8 bfr[2];
    #pragma unroll
    for (int ks = 0; ks < 2; ++ks){
      H8 t; int cb = ks*32 + g*8;
      #pragma unroll
      for (int k = 0; k < 8; ++k) t.s[k] = bands[3*BSLAB + (cb + k)*BSTR + pxb];
      bfr[ks] = t.v;
    }
    #pragma unroll
    for (int mi = 0; mi < 6; ++mi){
      int mt = ms*6 + mi;
      f32x4 acc = {0.f,0.f,0.f,0.f};
      #pragma unroll
      for (int ks = 0; ks < 2; ++ks){
        half8 a = *(const half8*)&wH[(mt*16 + mrow)*64 + ks*32 + g*8];
        acc = __builtin_amdgcn_mfma_f32_16x16x32_f16(a, bfr[ks], acc, 0, 0, 0);
      }
      #pragma unroll
      for (int r = 0; r < 4; ++r){
        int tl = mt*16 + g*4 + r;
        int G = tl >> 2, n = tl & 3;
        qk[qidx(G, n>>1, wl) + (n&1)*4 + qq] = f2h(acc[r]);
      }
    }
  }
  __syncthreads();
  {
    const halfT sh = (halfT)0.25f;
    const half8 s8 = {sh,sh,sh,sh,sh,sh,sh,sh};
    H8 qg; qg.v = *(const half8*)&qk[qidx(m>>1, np, W)];
    qg.v = qg.v * s8;
    float sum0=0.f, sum1=0.f, po0[4]={0,0,0,0}, po1[4]={0,0,0,0};
    #pragma unroll
    for (int d = 0; d < 16; ++d){
      H8 kg, vg;
      kg.v = *(const half8*)&qk[qidx(16+d, np, W)];
      vg.v = *(const half8*)&qk[qidx(32+d, np, W)];
      float a0 = dot4(qg.h2[0], qg.h2[1], kg.h2[0], kg.h2[1]);
      float a1 = dot4(qg.h2[2], qg.h2[3], kg.h2[2], kg.h2[3]);
      float e0 = __expf(a0), e1 = __expf(a1);
      sum0 += e0; sum1 += e1;
      #pragma unroll
      for (int s2 = 0; s2 < 4; ++s2){
        po0[s2] += e0 * (float)vg.v[s2];
        po1[s2] += e1 * (float)vg.v[4+s2];
      }
    }
    float i0 = __builtin_amdgcn_rcpf(sum0), i1 = __builtin_amdgcn_rcpf(sum1);
    #pragma unroll
    for (int s2 = 0; s2 < 4; ++s2){ y3[0][s2] = po0[s2]*i0; y3[1][s2] = po1[s2]*i1; }
  }
  __syncthreads();   // all qk/bands reads done; smem becomes ot

  // ============ iDWT in registers -> ot staging (LDS) =====================
  {
    const int gw = W ^ (m & 15);
    #pragma unroll
    for (int chi = 0; chi < 2; ++chi){
      int ch = A + chi;
      float* otc = ot + ch*OT_CS + gw*4;
      #pragma unroll
      for (int rp = 0; rp < 2; ++rp){
        float4 top, bot;
        #pragma unroll
        for (int cp = 0; cp < 2; ++cp){
          int s2 = rp*2 + cp;
          float ll = y0[chi][s2], lh = y1[chi][s2];
          float hl = y2[chi][s2], hh = y3[chi][s2];
          float va = 0.5f*(ll - lh - hl + hh);
          float vb = 0.5f*(ll - lh + hl - hh);
          float vc = 0.5f*(ll + lh - hl - hh);
          float vd = 0.5f*(ll + lh + hl + hh);
          if (cp == 0){ top.x = va; top.y = vb; bot.x = vc; bot.y = vd; }
          else        { top.z = va; top.w = vb; bot.z = vc; bot.w = vd; }
        }
        *(float4*)&otc[(2*rp)*OT_RS]   = top;
        *(float4*)&otc[(2*rp+1)*OT_RS] = bot;
      }
    }
  }
  __syncthreads();

  // ================= coalesced store (full-line writes) ===================
  #pragma unroll
  for (int it = 0; it < 2; ++it){
    int s = it*512 + tid;
    int ch = s >> 4, row = (s >> 2) & 3, seg = s & 3;
    int sw = (ch >> 1) & 15;
    const float* rowp = &ot[ch*OT_CS + row*OT_RS];
    float4 v0 = *(const float4*)&rowp[((seg*4+0) ^ sw)*4];
    float4 v1 = *(const float4*)&rowp[((seg*4+1) ^ sw)*4];
    float4 v2 = *(const float4*)&rowp[((seg*4+2) ^ sw)*4];
    float4 v3 = *(const float4*)&rowp[((seg*4+3) ^ sw)*4];
    float* dst = out + (((size_t)b*64 + ch)*256 + (size_t)(4*hw + row))*256 + col0 + seg*16;
    ((float4*)dst)[0] = v0; ((float4*)dst)[1] = v1;
    ((float4*)dst)[2] = v2; ((float4*)dst)[3] = v3;
  }
}

// ---------------------------------------------------------------------------
extern "C" void kernel_launch(void* const* d_in, const int* in_sizes, int n_in,
                              void* d_out, int out_size, void* d_ws, size_t ws_size,
                              hipStream_t stream){
  const float* x   = (const float*)d_in[0];
  const float* wlh = (const float*)d_in[1];
  const float* wm  = (const float*)d_in[2];
  float* out = (float*)d_out;
  halfT* wH = (halfT*)d_ws;                // 61440 f16 = 122880 B

  hipLaunchKernelGGL(k_wt,    dim3(240),  dim3(256), 0, stream, wlh, wm, wH);
  hipLaunchKernelGGL(k_fused, dim3(2048), dim3(512), 0, stream, x, wH, out);
}

// Round 9
// 247.244 us; speedup vs baseline: 3.1789x; 3.0385x over previous
//
#include <hip/hip_runtime.h>
#include <stdint.h>

// ---------------------------------------------------------------------------
// Fused wavelet window-attention, register-y / per-lane softmax / no-spill.
//   Block = 512 thr: one (unit, quarter) = 4 orig rows x 64 orig cols.
//   smem 80KB = bands[4][c64][px64] f16, XOR-swz px^(((c>>3)&3)<<4) (32KB)
//             + qk 48KB (G 0..95: mid Q|K|V = 32 G-groups each).
//   qk granule(G,np,wl) 16B = channels {4G+2np, +1} x q(4 spatial).
//   Mid attention is SINGLE-PASS (no accumulators across barriers -> no
//   spills; R6-R8's 2-pass mid caused ~1.9GB scratch traffic).
//   End: smem reused as ot[f32] ch*276+row*68, XOR-swz granules; coalesced
//   full-line stores (R8-verified).
// ---------------------------------------------------------------------------

typedef _Float16 halfT;
typedef __attribute__((ext_vector_type(2))) _Float16 half2T;
typedef __attribute__((ext_vector_type(8))) _Float16 half8;
typedef __attribute__((ext_vector_type(4))) float f32x4;

union H8 { half8 v; half2T h2[4]; uint16_t s[8]; };

static __device__ __forceinline__ uint16_t f2h(float f){
  union { halfT h; uint16_t u; } x; x.h = (halfT)f; return x.u;
}
static __device__ __forceinline__ float dot4(half2T a0, half2T a1,
                                             half2T b0, half2T b1){
#if __has_builtin(__builtin_amdgcn_fdot2)
  return __builtin_amdgcn_fdot2(a1, b1, __builtin_amdgcn_fdot2(a0, b0, 0.f, false), false);
#else
  half2T p = a0*b0 + a1*b1;
  return (float)p.x + (float)p.y;
#endif
}

__global__ void k_wt(const float* __restrict__ wlh, const float* __restrict__ wm,
                     halfT* __restrict__ wH){
  int i = blockIdx.x * 256 + threadIdx.x;
  if (i < 12288)      wH[i] = (halfT)wlh[i];
  else if (i < 61440) wH[i] = (halfT)wm[i - 12288];
}

#define OT_CS 276
#define OT_RS 68

static __device__ __forceinline__ int qidx(int G, int np, int W){
  return G*256 + np*128 + ((W ^ (G & 7)) << 3);
}

// low/high conv: K=64, T=192; band slab, 12 M-tiles split by ms
static __device__ __forceinline__ void conv64(const halfT* __restrict__ w,
    const uint16_t* __restrict__ bands, uint16_t* __restrict__ qk,
    int band, int mrow, int g, int ms, int pxb, int wl, int qq){
  half8 bfr[2];
  #pragma unroll
  for (int ks = 0; ks < 2; ++ks){
    H8 t; int cb = ks*32 + g*8;
    #pragma unroll
    for (int k = 0; k < 8; ++k)
      t.s[k] = bands[band*4096 + (cb + k)*64 + (pxb ^ (g << 4))];
    bfr[ks] = t.v;
  }
  #pragma unroll
  for (int mi = 0; mi < 6; ++mi){
    int mt = ms*6 + mi;
    f32x4 acc = {0.f,0.f,0.f,0.f};
    #pragma unroll
    for (int ks = 0; ks < 2; ++ks){
      half8 a = *(const half8*)&w[(mt*16 + mrow)*64 + ks*32 + g*8];
      acc = __builtin_amdgcn_mfma_f32_16x16x32_f16(a, bfr[ks], acc, 0, 0, 0);
    }
    #pragma unroll
    for (int r = 0; r < 4; ++r){
      int tl = mt*16 + g*4 + r;
      qk[qidx(tl >> 2, (tl & 3) >> 1, wl) + (tl & 1)*4 + qq] = f2h(acc[r]);
    }
  }
}

// low/high attention: c=16/head, d over 16 c_idx groups; Q G0-15,K 16-31,V 32-47
static __device__ __forceinline__ void attn16(const uint16_t* __restrict__ qk,
    int m, int np, int W, float y[2][4]){
  const halfT sh = (halfT)0.25f;
  const half8 s8 = {sh,sh,sh,sh,sh,sh,sh,sh};
  H8 qg; qg.v = (*(const half8*)&qk[qidx(m >> 1, np, W)]) * s8;
  float sum0 = 0.f, sum1 = 0.f, po0[4] = {0,0,0,0}, po1[4] = {0,0,0,0};
  #pragma unroll
  for (int d = 0; d < 16; ++d){
    H8 kg, vg;
    kg.v = *(const half8*)&qk[qidx(16 + d, np, W)];
    vg.v = *(const half8*)&qk[qidx(32 + d, np, W)];
    float a0 = dot4(qg.h2[0], qg.h2[1], kg.h2[0], kg.h2[1]);
    float a1 = dot4(qg.h2[2], qg.h2[3], kg.h2[2], kg.h2[3]);
    float e0 = __expf(a0), e1 = __expf(a1);
    sum0 += e0; sum1 += e1;
    #pragma unroll
    for (int s2 = 0; s2 < 4; ++s2){
      po0[s2] += e0 * (float)vg.v[s2];
      po1[s2] += e1 * (float)vg.v[4 + s2];
    }
  }
  float i0 = __builtin_amdgcn_rcpf(sum0), i1 = __builtin_amdgcn_rcpf(sum1);
  #pragma unroll
  for (int s2 = 0; s2 < 4; ++s2){ y[0][s2] = po0[s2]*i0; y[1][s2] = po1[s2]*i1; }
}

__global__ __launch_bounds__(512, 4) void k_fused(const float* __restrict__ x,
    const halfT* __restrict__ wH, float* __restrict__ out){
  __shared__ __align__(16) uint8_t smem[81920];
  uint16_t* bands = (uint16_t*)smem;                 // 32768 B
  uint16_t* qk    = (uint16_t*)(smem + 32768);       // 49152 B
  float*    ot    = (float*)smem;                    // reused at end

  const int tid = threadIdx.x;
  const int wv = tid >> 6, lane = tid & 63;
  const int unit = blockIdx.x >> 2, q4 = blockIdx.x & 3;
  const int b = unit >> 6, hw = unit & 63;
  const int col0 = q4 * 64;
  const float* xb = x + (size_t)b * 64 * 65536;
  const halfT* wM = wH + 12288;

  // ---------------- phase A: load x + Haar DWT -> bands -------------------
  #pragma unroll
  for (int it = 0; it < 4; ++it){
    int idx = it*512 + tid;
    int j = idx & 15, rp = (idx >> 4) & 1, c = idx >> 5;
    const float* src = xb + (size_t)c*65536 + (size_t)(4*hw + 2*rp)*256 + col0 + 4*j;
    float4 r0 = *(const float4*)src;
    float4 r1 = *(const float4*)(src + 256);
    float v0[4], v1[4];
    v0[0] = 0.5f*( r0.x + r0.y + r1.x + r1.y);
    v0[1] = 0.5f*(-r0.x - r0.y + r1.x + r1.y);
    v0[2] = 0.5f*(-r0.x + r0.y - r1.x + r1.y);
    v0[3] = 0.5f*( r0.x - r0.y - r1.x + r1.y);
    v1[0] = 0.5f*( r0.z + r0.w + r1.z + r1.w);
    v1[1] = 0.5f*(-r0.z - r0.w + r1.z + r1.w);
    v1[2] = 0.5f*(-r0.z + r0.w - r1.z + r1.w);
    v1[3] = 0.5f*( r0.z - r0.w - r1.z + r1.w);
    int base = c*64 + ((rp*32 + 2*j) ^ (((c >> 3) & 3) << 4));
    #pragma unroll
    for (int bb = 0; bb < 4; ++bb)
      *(uint32_t*)&bands[bb*4096 + base] =
          (uint32_t)f2h(v0[bb]) | ((uint32_t)f2h(v1[bb]) << 16);
  }
  __syncthreads();

  const int mrow = lane & 15, g = lane >> 4;
  const int m = lane & 31;
  const int W = wv*2 + (lane >> 5);   // window 0..15, fixed per thread
  const int A = 2*m;                  // output ch pair base
  const int np = m & 1;
  const int pxb = (wv & 3)*16 + mrow; // conv N-column
  const int wl = (pxb & 31) >> 1, qq = (pxb >> 5)*2 + (pxb & 1);
  const int ms = wv >> 2;

  float y0[2][4], y1[2][4], y2[2][4], y3[2][4];

  // ---- LOW ----
  conv64(wH, bands, qk, 0, mrow, g, ms, pxb, wl, qq);
  __syncthreads();
  attn16(qk, m, np, W, y0);
  __syncthreads();

  // ---- MID conv: K=128 (bands 1,2), T=384, 24 M-tiles split by ms ----
  {
    half8 bfr[4];
    #pragma unroll
    for (int ks = 0; ks < 4; ++ks){
      H8 t; int band = 1 + (ks >> 1); int cb = (ks & 1)*32 + g*8;
      #pragma unroll
      for (int k = 0; k < 8; ++k)
        t.s[k] = bands[band*4096 + (cb + k)*64 + (pxb ^ (g << 4))];
      bfr[ks] = t.v;
    }
    #pragma unroll
    for (int mi = 0; mi < 12; ++mi){
      int mt = ms*12 + mi;
      f32x4 acc = {0.f,0.f,0.f,0.f};
      #pragma unroll
      for (int ks = 0; ks < 4; ++ks){
        half8 a = *(const half8*)&wM[(mt*16 + mrow)*128 + ks*32 + g*8];
        acc = __builtin_amdgcn_mfma_f32_16x16x32_f16(a, bfr[ks], acc, 0, 0, 0);
      }
      #pragma unroll
      for (int r = 0; r < 4; ++r){
        int tl = mt*16 + g*4 + r;              // 0..383 -> G 0..95
        qk[qidx(tl >> 2, (tl & 3) >> 1, wl) + (tl & 1)*4 + qq] = f2h(acc[r]);
      }
    }
  }
  __syncthreads();

  // ---- MID attention: single pass, c=32/head; Q G0-31, K 32-63, V 64-95 ----
  {
    const halfT shm = (halfT)0.17677669529663687f;
    const half8 s8m = {shm,shm,shm,shm,shm,shm,shm,shm};
    H8 qa, qb;
    qa.v = (*(const half8*)&qk[qidx(m >> 1, np, W)]) * s8m;        // lh rows A,A+1
    qb.v = (*(const half8*)&qk[qidx(16 + (m >> 1), np, W)]) * s8m; // hl rows 64+A
    float sum[4] = {0,0,0,0};
    float po[4][4] = {{0,0,0,0},{0,0,0,0},{0,0,0,0},{0,0,0,0}};
    #pragma unroll
    for (int dl = 0; dl < 32; ++dl){
      H8 kg, vg;
      kg.v = *(const half8*)&qk[qidx(32 + dl, np, W)];
      vg.v = *(const half8*)&qk[qidx(64 + dl, np, W)];
      float a0 = dot4(qa.h2[0], qa.h2[1], kg.h2[0], kg.h2[1]);
      float a1 = dot4(qa.h2[2], qa.h2[3], kg.h2[2], kg.h2[3]);
      float a2 = dot4(qb.h2[0], qb.h2[1], kg.h2[0], kg.h2[1]);
      float a3 = dot4(qb.h2[2], qb.h2[3], kg.h2[2], kg.h2[3]);
      float e0 = __expf(a0), e1 = __expf(a1);
      float e2 = __expf(a2), e3 = __expf(a3);
      sum[0] += e0; sum[1] += e1; sum[2] += e2; sum[3] += e3;
      #pragma unroll
      for (int s2 = 0; s2 < 4; ++s2){
        float vlo = (float)vg.v[s2], vhi = (float)vg.v[4 + s2];
        po[0][s2] += e0*vlo; po[1][s2] += e1*vhi;
        po[2][s2] += e2*vlo; po[3][s2] += e3*vhi;
      }
    }
    float i0 = __builtin_amdgcn_rcpf(sum[0]), i1 = __builtin_amdgcn_rcpf(sum[1]);
    float i2 = __builtin_amdgcn_rcpf(sum[2]), i3 = __builtin_amdgcn_rcpf(sum[3]);
    #pragma unroll
    for (int s2 = 0; s2 < 4; ++s2){
      y1[0][s2] = po[0][s2]*i0; y1[1][s2] = po[1][s2]*i1;
      y2[0][s2] = po[2][s2]*i2; y2[1][s2] = po[3][s2]*i3;
    }
  }
  __syncthreads();

  // ---- HIGH ----
  conv64(wH, bands, qk, 3, mrow, g, ms, pxb, wl, qq);
  __syncthreads();
  attn16(qk, m, np, W, y3);
  __syncthreads();   // last smem read done; smem becomes ot

  // ---- iDWT in registers -> ot staging ----
  {
    const int gw = W ^ (m & 15);
    #pragma unroll
    for (int chi = 0; chi < 2; ++chi){
      int ch = A + chi;
      float* otc = ot + ch*OT_CS + gw*4;
      #pragma unroll
      for (int rp = 0; rp < 2; ++rp){
        float4 top, bot;
        #pragma unroll
        for (int cp = 0; cp < 2; ++cp){
          int s2 = rp*2 + cp;
          float ll = y0[chi][s2], lh = y1[chi][s2];
          float hl = y2[chi][s2], hh = y3[chi][s2];
          float va = 0.5f*(ll - lh - hl + hh);
          float vb = 0.5f*(ll - lh + hl - hh);
          float vc = 0.5f*(ll + lh - hl - hh);
          float vd = 0.5f*(ll + lh + hl + hh);
          if (cp == 0){ top.x = va; top.y = vb; bot.x = vc; bot.y = vd; }
          else        { top.z = va; top.w = vb; bot.z = vc; bot.w = vd; }
        }
        *(float4*)&otc[(2*rp)*OT_RS]   = top;
        *(float4*)&otc[(2*rp+1)*OT_RS] = bot;
      }
    }
  }
  __syncthreads();

  // ---- coalesced store (full-line writes) ----
  #pragma unroll
  for (int it = 0; it < 2; ++it){
    int s = it*512 + tid;
    int ch = s >> 4, row = (s >> 2) & 3, seg = s & 3;
    int sw = (ch >> 1) & 15;
    const float* rowp = &ot[ch*OT_CS + row*OT_RS];
    float4 v0 = *(const float4*)&rowp[((seg*4+0) ^ sw)*4];
    float4 v1 = *(const float4*)&rowp[((seg*4+1) ^ sw)*4];
    float4 v2 = *(const float4*)&rowp[((seg*4+2) ^ sw)*4];
    float4 v3 = *(const float4*)&rowp[((seg*4+3) ^ sw)*4];
    float* dst = out + (((size_t)b*64 + ch)*256 + (size_t)(4*hw + row))*256 + col0 + seg*16;
    ((float4*)dst)[0] = v0; ((float4*)dst)[1] = v1;
    ((float4*)dst)[2] = v2; ((float4*)dst)[3] = v3;
  }
}

// ---------------------------------------------------------------------------
extern "C" void kernel_launch(void* const* d_in, const int* in_sizes, int n_in,
                              void* d_out, int out_size, void* d_ws, size_t ws_size,
                              hipStream_t stream){
  const float* x   = (const float*)d_in[0];
  const float* wlh = (const float*)d_in[1];
  const float* wm  = (const float*)d_in[2];
  float* out = (float*)d_out;
  halfT* wH = (halfT*)d_ws;                // 61440 f16 = 122880 B

  hipLaunchKernelGGL(k_wt,    dim3(240),  dim3(256), 0, stream, wlh, wm, wH);
  hipLaunchKernelGGL(k_fused, dim3(2048), dim3(512), 0, stream, x, wH, out);
}

// Round 10
// 232.769 us; speedup vs baseline: 3.3766x; 1.0622x over previous
//
#include <hip/hip_runtime.h>
#include <stdint.h>

// ---------------------------------------------------------------------------
// Fused wavelet window-attention, register-y / per-lane softmax / no-spill.
//   Block = 512 thr: one (unit, quarter) = 4 orig rows x 64 orig cols.
//   smem 80KB = bands[4][c64][px64] f16 XOR-swz (32KB) + qk 48KB.
//   qk granule(G,np,W) 16B = channels {4G+2np, +1} x q(4 spatial).
//   Head = ch&3 (reference reshape is (c, NUM_HEADS)): granule (G,np) holds
//   head pair {2np, 2np+1}; d-loop over G covers exactly one head per e-slot.
//   R10: amdgpu_waves_per_eu(4,4) (LDS caps occupancy at 4 waves/SIMD anyway)
//   so the allocator stops spilling y-state to scratch (R9: 134MB spill WRITE).
//   All accumulators are named f32x4 (nothing stack-allocatable).
// ---------------------------------------------------------------------------

typedef _Float16 halfT;
typedef __attribute__((ext_vector_type(2))) _Float16 half2T;
typedef __attribute__((ext_vector_type(8))) _Float16 half8;
typedef __attribute__((ext_vector_type(4))) float f32x4;

union H8 { half8 v; half2T h2[4]; uint16_t s[8]; };

static __device__ __forceinline__ uint16_t f2h(float f){
  union { halfT h; uint16_t u; } x; x.h = (halfT)f; return x.u;
}
static __device__ __forceinline__ float dot4(half2T a0, half2T a1,
                                             half2T b0, half2T b1){
#if __has_builtin(__builtin_amdgcn_fdot2)
  return __builtin_amdgcn_fdot2(a1, b1, __builtin_amdgcn_fdot2(a0, b0, 0.f, false), false);
#else
  half2T p = a0*b0 + a1*b1;
  return (float)p.x + (float)p.y;
#endif
}

__global__ void k_wt(const float* __restrict__ wlh, const float* __restrict__ wm,
                     halfT* __restrict__ wH){
  int i = blockIdx.x * 256 + threadIdx.x;
  if (i < 12288)      wH[i] = (halfT)wlh[i];
  else if (i < 61440) wH[i] = (halfT)wm[i - 12288];
}

#define OT_CS 276
#define OT_RS 68

static __device__ __forceinline__ int qidx(int G, int np, int W){
  return G*256 + np*128 + ((W ^ (G & 7)) << 3);
}

// low/high conv: K=64, T=192; 12 M-tiles split by ms
static __device__ __forceinline__ void conv64(const halfT* __restrict__ w,
    const uint16_t* __restrict__ bands, uint16_t* __restrict__ qk,
    int band, int mrow, int g, int ms, int pxb, int wl, int qq){
  half8 bfr[2];
  #pragma unroll
  for (int ks = 0; ks < 2; ++ks){
    H8 t; int cb = ks*32 + g*8;
    #pragma unroll
    for (int k = 0; k < 8; ++k)
      t.s[k] = bands[band*4096 + (cb + k)*64 + (pxb ^ (g << 4))];
    bfr[ks] = t.v;
  }
  #pragma unroll
  for (int mi = 0; mi < 6; ++mi){
    int mt = ms*6 + mi;
    f32x4 acc = {0.f,0.f,0.f,0.f};
    #pragma unroll
    for (int ks = 0; ks < 2; ++ks){
      half8 a = *(const half8*)&w[(mt*16 + mrow)*64 + ks*32 + g*8];
      acc = __builtin_amdgcn_mfma_f32_16x16x32_f16(a, bfr[ks], acc, 0, 0, 0);
    }
    #pragma unroll
    for (int r = 0; r < 4; ++r){
      int tl = mt*16 + g*4 + r;
      qk[qidx(tl >> 2, (tl & 3) >> 1, wl) + (tl & 1)*4 + qq] = f2h(acc[r]);
    }
  }
}

// low/high attention: heads {2np, 2np+1}; Q G0-15, K 16-31, V 32-47
static __device__ __forceinline__ void attn16(const uint16_t* __restrict__ qk,
    int m, int np, int W, f32x4& ylo, f32x4& yhi){
  const halfT sh = (halfT)0.25f;
  const half8 s8 = {sh,sh,sh,sh,sh,sh,sh,sh};
  H8 qg; qg.v = (*(const half8*)&qk[qidx(m >> 1, np, W)]) * s8;
  float sum0 = 0.f, sum1 = 0.f;
  f32x4 po0 = {0.f,0.f,0.f,0.f}, po1 = {0.f,0.f,0.f,0.f};
  #pragma unroll
  for (int d = 0; d < 16; ++d){
    H8 kg, vg;
    kg.v = *(const half8*)&qk[qidx(16 + d, np, W)];
    vg.v = *(const half8*)&qk[qidx(32 + d, np, W)];
    float a0 = dot4(qg.h2[0], qg.h2[1], kg.h2[0], kg.h2[1]);
    float a1 = dot4(qg.h2[2], qg.h2[3], kg.h2[2], kg.h2[3]);
    float e0 = __expf(a0), e1 = __expf(a1);
    sum0 += e0; sum1 += e1;
    #pragma unroll
    for (int s2 = 0; s2 < 4; ++s2){
      po0[s2] += e0 * (float)vg.v[s2];
      po1[s2] += e1 * (float)vg.v[4 + s2];
    }
  }
  ylo = po0 * __builtin_amdgcn_rcpf(sum0);
  yhi = po1 * __builtin_amdgcn_rcpf(sum1);
}

#define IDWT(CH, Y0, Y1, Y2, Y3) { \
  float* otc = ot + (CH)*OT_CS + gw*4; \
  _Pragma("unroll") \
  for (int rp = 0; rp < 2; ++rp){ \
    float4 top, bot; \
    _Pragma("unroll") \
    for (int cp = 0; cp < 2; ++cp){ \
      int s2 = rp*2 + cp; \
      float ll = Y0[s2], lh = Y1[s2], hl = Y2[s2], hh = Y3[s2]; \
      float va = 0.5f*(ll - lh - hl + hh); \
      float vb = 0.5f*(ll - lh + hl - hh); \
      float vc = 0.5f*(ll + lh - hl - hh); \
      float vd = 0.5f*(ll + lh + hl + hh); \
      if (cp == 0){ top.x = va; top.y = vb; bot.x = vc; bot.y = vd; } \
      else        { top.z = va; top.w = vb; bot.z = vc; bot.w = vd; } \
    } \
    *(float4*)&otc[(2*rp)*OT_RS]   = top; \
    *(float4*)&otc[(2*rp+1)*OT_RS] = bot; \
  } }

__global__ __launch_bounds__(512)
__attribute__((amdgpu_waves_per_eu(4, 4)))
void k_fused(const float* __restrict__ x,
    const halfT* __restrict__ wH, float* __restrict__ out){
  __shared__ __align__(16) uint8_t smem[81920];
  uint16_t* bands = (uint16_t*)smem;                 // 32768 B
  uint16_t* qk    = (uint16_t*)(smem + 32768);       // 49152 B
  float*    ot    = (float*)smem;                    // reused at end

  const int tid = threadIdx.x;
  const int wv = tid >> 6, lane = tid & 63;
  const int unit = blockIdx.x >> 2, q4 = blockIdx.x & 3;
  const int b = unit >> 6, hw = unit & 63;
  const int col0 = q4 * 64;
  const float* xb = x + (size_t)b * 64 * 65536;
  const halfT* wM = wH + 12288;

  // ---------------- phase A: load x + Haar DWT -> bands -------------------
  #pragma unroll
  for (int it = 0; it < 4; ++it){
    int idx = it*512 + tid;
    int j = idx & 15, rp = (idx >> 4) & 1, c = idx >> 5;
    const float* src = xb + (size_t)c*65536 + (size_t)(4*hw + 2*rp)*256 + col0 + 4*j;
    float4 r0 = *(const float4*)src;
    float4 r1 = *(const float4*)(src + 256);
    float v0[4], v1[4];
    v0[0] = 0.5f*( r0.x + r0.y + r1.x + r1.y);
    v0[1] = 0.5f*(-r0.x - r0.y + r1.x + r1.y);
    v0[2] = 0.5f*(-r0.x + r0.y - r1.x + r1.y);
    v0[3] = 0.5f*( r0.x - r0.y - r1.x + r1.y);
    v1[0] = 0.5f*( r0.z + r0.w + r1.z + r1.w);
    v1[1] = 0.5f*(-r0.z - r0.w + r1.z + r1.w);
    v1[2] = 0.5f*(-r0.z + r0.w - r1.z + r1.w);
    v1[3] = 0.5f*( r0.z - r0.w - r1.z + r1.w);
    int base = c*64 + ((rp*32 + 2*j) ^ (((c >> 3) & 3) << 4));
    #pragma unroll
    for (int bb = 0; bb < 4; ++bb)
      *(uint32_t*)&bands[bb*4096 + base] =
          (uint32_t)f2h(v0[bb]) | ((uint32_t)f2h(v1[bb]) << 16);
  }
  __syncthreads();

  const int mrow = lane & 15, g = lane >> 4;
  const int m = lane & 31;
  const int W = wv*2 + (lane >> 5);   // window 0..15, fixed per thread
  const int A = 2*m;                  // output ch pair base
  const int np = m & 1;
  const int pxb = (wv & 3)*16 + mrow; // conv N-column
  const int wl = (pxb & 31) >> 1, qq = (pxb >> 5)*2 + (pxb & 1);
  const int ms = wv >> 2;

  f32x4 y0l, y0h, y1l, y1h, y2l, y2h, y3l, y3h;

  // ---- LOW ----
  conv64(wH, bands, qk, 0, mrow, g, ms, pxb, wl, qq);
  __syncthreads();
  attn16(qk, m, np, W, y0l, y0h);
  __syncthreads();

  // ---- MID conv: K=128 (bands 1,2), T=384, 24 M-tiles split by ms ----
  {
    half8 bfr[4];
    #pragma unroll
    for (int ks = 0; ks < 4; ++ks){
      H8 t; int band = 1 + (ks >> 1); int cb = (ks & 1)*32 + g*8;
      #pragma unroll
      for (int k = 0; k < 8; ++k)
        t.s[k] = bands[band*4096 + (cb + k)*64 + (pxb ^ (g << 4))];
      bfr[ks] = t.v;
    }
    #pragma unroll
    for (int mi = 0; mi < 12; ++mi){
      int mt = ms*12 + mi;
      f32x4 acc = {0.f,0.f,0.f,0.f};
      #pragma unroll
      for (int ks = 0; ks < 4; ++ks){
        half8 a = *(const half8*)&wM[(mt*16 + mrow)*128 + ks*32 + g*8];
        acc = __builtin_amdgcn_mfma_f32_16x16x32_f16(a, bfr[ks], acc, 0, 0, 0);
      }
      #pragma unroll
      for (int r = 0; r < 4; ++r){
        int tl = mt*16 + g*4 + r;              // 0..383 -> G 0..95
        qk[qidx(tl >> 2, (tl & 3) >> 1, wl) + (tl & 1)*4 + qq] = f2h(acc[r]);
      }
    }
  }
  __syncthreads();

  // ---- MID attention: single pass; Q G0-31, K 32-63, V 64-95 ----
  {
    const halfT shm = (halfT)0.17677669529663687f;
    const half8 s8m = {shm,shm,shm,shm,shm,shm,shm,shm};
    H8 qa, qb;
    qa.v = (*(const half8*)&qk[qidx(m >> 1, np, W)]) * s8m;        // lh rows
    qb.v = (*(const half8*)&qk[qidx(16 + (m >> 1), np, W)]) * s8m; // hl rows
    float sm0 = 0.f, sm1 = 0.f, sm2 = 0.f, sm3 = 0.f;
    f32x4 p0 = {0.f,0.f,0.f,0.f}, p1 = {0.f,0.f,0.f,0.f};
    f32x4 p2 = {0.f,0.f,0.f,0.f}, p3 = {0.f,0.f,0.f,0.f};
    #pragma unroll
    for (int dl = 0; dl < 32; ++dl){
      H8 kg, vg;
      kg.v = *(const half8*)&qk[qidx(32 + dl, np, W)];
      vg.v = *(const half8*)&qk[qidx(64 + dl, np, W)];
      float a0 = dot4(qa.h2[0], qa.h2[1], kg.h2[0], kg.h2[1]);
      float a1 = dot4(qa.h2[2], qa.h2[3], kg.h2[2], kg.h2[3]);
      float a2 = dot4(qb.h2[0], qb.h2[1], kg.h2[0], kg.h2[1]);
      float a3 = dot4(qb.h2[2], qb.h2[3], kg.h2[2], kg.h2[3]);
      float e0 = __expf(a0), e1 = __expf(a1);
      float e2 = __expf(a2), e3 = __expf(a3);
      sm0 += e0; sm1 += e1; sm2 += e2; sm3 += e3;
      #pragma unroll
      for (int s2 = 0; s2 < 4; ++s2){
        float vlo = (float)vg.v[s2], vhi = (float)vg.v[4 + s2];
        p0[s2] += e0*vlo; p1[s2] += e1*vhi;
        p2[s2] += e2*vlo; p3[s2] += e3*vhi;
      }
    }
    y1l = p0 * __builtin_amdgcn_rcpf(sm0);
    y1h = p1 * __builtin_amdgcn_rcpf(sm1);
    y2l = p2 * __builtin_amdgcn_rcpf(sm2);
    y2h = p3 * __builtin_amdgcn_rcpf(sm3);
  }
  __syncthreads();

  // ---- HIGH ----
  conv64(wH, bands, qk, 3, mrow, g, ms, pxb, wl, qq);
  __syncthreads();
  attn16(qk, m, np, W, y3l, y3h);
  __syncthreads();   // last smem read done; smem becomes ot

  // ---- iDWT in registers -> ot staging ----
  {
    const int gw = W ^ (m & 15);
    IDWT(A,     y0l, y1l, y2l, y3l);
    IDWT(A + 1, y0h, y1h, y2h, y3h);
  }
  __syncthreads();

  // ---- coalesced store (full-line writes) ----
  #pragma unroll
  for (int it = 0; it < 2; ++it){
    int s = it*512 + tid;
    int ch = s >> 4, row = (s >> 2) & 3, seg = s & 3;
    int sw = (ch >> 1) & 15;
    const float* rowp = &ot[ch*OT_CS + row*OT_RS];
    float4 v0 = *(const float4*)&rowp[((seg*4+0) ^ sw)*4];
    float4 v1 = *(const float4*)&rowp[((seg*4+1) ^ sw)*4];
    float4 v2 = *(const float4*)&rowp[((seg*4+2) ^ sw)*4];
    float4 v3 = *(const float4*)&rowp[((seg*4+3) ^ sw)*4];
    float* dst = out + (((size_t)b*64 + ch)*256 + (size_t)(4*hw + row))*256 + col0 + seg*16;
    ((float4*)dst)[0] = v0; ((float4*)dst)[1] = v1;
    ((float4*)dst)[2] = v2; ((float4*)dst)[3] = v3;
  }
}

// ---------------------------------------------------------------------------
extern "C" void kernel_launch(void* const* d_in, const int* in_sizes, int n_in,
                              void* d_out, int out_size, void* d_ws, size_t ws_size,
                              hipStream_t stream){
  const float* x   = (const float*)d_in[0];
  const float* wlh = (const float*)d_in[1];
  const float* wm  = (const float*)d_in[2];
  float* out = (float*)d_out;
  halfT* wH = (halfT*)d_ws;                // 61440 f16 = 122880 B

  hipLaunchKernelGGL(k_wt,    dim3(240),  dim3(256), 0, stream, wlh, wm, wH);
  hipLaunchKernelGGL(k_fused, dim3(2048), dim3(512), 0, stream, x, wH, out);
}

// Round 11
// 207.266 us; speedup vs baseline: 3.7921x; 1.1230x over previous
//
#include <hip/hip_runtime.h>
#include <stdint.h>

// ---------------------------------------------------------------------------
// Fused wavelet window-attention; y parked in dead LDS band slabs (no spill).
//   Block = 512 thr: one (unit, quarter) = 4 orig rows x 64 orig cols.
//   smem 80KB = bands[4][c64][px64] f16 XOR-swz (32KB) + qk 48KB.
//   qk granule(G,np,W) 16B = channels {4G+2np, +1} x q(4 spatial).
//   After each path's conv, its band slab is dead -> attention writes packed
//   f16 y pairs there ([w*512+tid] u32, conflict-free). y3 stays in regs.
//   R9/R10 lesson: y-state held in regs across 6 barriers spilled ~90-140MB
//   to scratch at the allocator's fixed 64-VGPR budget.
// ---------------------------------------------------------------------------

typedef _Float16 halfT;
typedef __attribute__((ext_vector_type(2))) _Float16 half2T;
typedef __attribute__((ext_vector_type(8))) _Float16 half8;
typedef __attribute__((ext_vector_type(4))) float f32x4;

union H8 { half8 v; half2T h2[4]; uint16_t s[8]; };

static __device__ __forceinline__ uint16_t f2h(float f){
  union { halfT h; uint16_t u; } x; x.h = (halfT)f; return x.u;
}
static __device__ __forceinline__ float h2f(uint16_t u){
  union { uint16_t u; halfT h; } x; x.u = u; return (float)x.h;
}
static __device__ __forceinline__ uint32_t pk16(float a, float b){
  return (uint32_t)f2h(a) | ((uint32_t)f2h(b) << 16);
}
static __device__ __forceinline__ float dot4(half2T a0, half2T a1,
                                             half2T b0, half2T b1){
#if __has_builtin(__builtin_amdgcn_fdot2)
  return __builtin_amdgcn_fdot2(a1, b1, __builtin_amdgcn_fdot2(a0, b0, 0.f, false), false);
#else
  half2T p = a0*b0 + a1*b1;
  return (float)p.x + (float)p.y;
#endif
}

__global__ void k_wt(const float* __restrict__ wlh, const float* __restrict__ wm,
                     halfT* __restrict__ wH){
  int i = blockIdx.x * 256 + threadIdx.x;
  if (i < 12288)      wH[i] = (halfT)wlh[i];
  else if (i < 61440) wH[i] = (halfT)wm[i - 12288];
}

#define OT_CS 276
#define OT_RS 68

static __device__ __forceinline__ int qidx(int G, int np, int W){
  return G*256 + np*128 + ((W ^ (G & 7)) << 3);
}

// low/high conv: K=64, T=192; 12 M-tiles split by ms
static __device__ __forceinline__ void conv64(const halfT* __restrict__ w,
    const uint16_t* __restrict__ bands, uint16_t* __restrict__ qk,
    int band, int mrow, int g, int ms, int pxb, int wl, int qq){
  half8 bfr[2];
  #pragma unroll
  for (int ks = 0; ks < 2; ++ks){
    H8 t; int cb = ks*32 + g*8;
    #pragma unroll
    for (int k = 0; k < 8; ++k)
      t.s[k] = bands[band*4096 + (cb + k)*64 + (pxb ^ (g << 4))];
    bfr[ks] = t.v;
  }
  #pragma unroll
  for (int mi = 0; mi < 6; ++mi){
    int mt = ms*6 + mi;
    f32x4 acc = {0.f,0.f,0.f,0.f};
    #pragma unroll
    for (int ks = 0; ks < 2; ++ks){
      half8 a = *(const half8*)&w[(mt*16 + mrow)*64 + ks*32 + g*8];
      acc = __builtin_amdgcn_mfma_f32_16x16x32_f16(a, bfr[ks], acc, 0, 0, 0);
    }
    #pragma unroll
    for (int r = 0; r < 4; ++r){
      int tl = mt*16 + g*4 + r;
      qk[qidx(tl >> 2, (tl & 3) >> 1, wl) + (tl & 1)*4 + qq] = f2h(acc[r]);
    }
  }
}

// low/high attention -> packed y into yslab (dead band region)
static __device__ __forceinline__ void attn16(const uint16_t* __restrict__ qk,
    int m, int np, int W, uint32_t* __restrict__ yslab, int tid){
  const halfT sh = (halfT)0.25f;
  const half8 s8 = {sh,sh,sh,sh,sh,sh,sh,sh};
  H8 qg; qg.v = (*(const half8*)&qk[qidx(m >> 1, np, W)]) * s8;
  float sum0 = 0.f, sum1 = 0.f;
  f32x4 po0 = {0.f,0.f,0.f,0.f}, po1 = {0.f,0.f,0.f,0.f};
  #pragma unroll
  for (int d = 0; d < 16; ++d){
    H8 kg, vg;
    kg.v = *(const half8*)&qk[qidx(16 + d, np, W)];
    vg.v = *(const half8*)&qk[qidx(32 + d, np, W)];
    float a0 = dot4(qg.h2[0], qg.h2[1], kg.h2[0], kg.h2[1]);
    float a1 = dot4(qg.h2[2], qg.h2[3], kg.h2[2], kg.h2[3]);
    float e0 = __expf(a0), e1 = __expf(a1);
    sum0 += e0; sum1 += e1;
    #pragma unroll
    for (int s2 = 0; s2 < 4; ++s2){
      po0[s2] += e0 * (float)vg.v[s2];
      po1[s2] += e1 * (float)vg.v[4 + s2];
    }
  }
  float i0 = __builtin_amdgcn_rcpf(sum0), i1 = __builtin_amdgcn_rcpf(sum1);
  yslab[0*512 + tid] = pk16(po0[0]*i0, po0[1]*i0);
  yslab[1*512 + tid] = pk16(po0[2]*i0, po0[3]*i0);
  yslab[2*512 + tid] = pk16(po1[0]*i1, po1[1]*i1);
  yslab[3*512 + tid] = pk16(po1[2]*i1, po1[3]*i1);
}

#define IDWT(CH, Y0, Y1, Y2, Y3) { \
  float* otc = ot + (CH)*OT_CS + gw*4; \
  _Pragma("unroll") \
  for (int rp = 0; rp < 2; ++rp){ \
    float4 top, bot; \
    _Pragma("unroll") \
    for (int cp = 0; cp < 2; ++cp){ \
      int s2 = rp*2 + cp; \
      float ll = Y0[s2], lh = Y1[s2], hl = Y2[s2], hh = Y3[s2]; \
      float va = 0.5f*(ll - lh - hl + hh); \
      float vb = 0.5f*(ll - lh + hl - hh); \
      float vc = 0.5f*(ll + lh - hl - hh); \
      float vd = 0.5f*(ll + lh + hl + hh); \
      if (cp == 0){ top.x = va; top.y = vb; bot.x = vc; bot.y = vd; } \
      else        { top.z = va; top.w = vb; bot.z = vc; bot.w = vd; } \
    } \
    *(float4*)&otc[(2*rp)*OT_RS]   = top; \
    *(float4*)&otc[(2*rp+1)*OT_RS] = bot; \
  } }

__global__ __launch_bounds__(512, 4) void k_fused(const float* __restrict__ x,
    const halfT* __restrict__ wH, float* __restrict__ out){
  __shared__ __align__(16) uint8_t smem[81920];
  uint16_t* bands = (uint16_t*)smem;                 // 32768 B
  uint16_t* qk    = (uint16_t*)(smem + 32768);       // 49152 B
  uint32_t* ybuf  = (uint32_t*)smem;                 // y slabs (dead bands)
  float*    ot    = (float*)smem;                    // reused at end

  const int tid = threadIdx.x;
  const int wv = tid >> 6, lane = tid & 63;
  const int unit = blockIdx.x >> 2, q4 = blockIdx.x & 3;
  const int b = unit >> 6, hw = unit & 63;
  const int col0 = q4 * 64;
  const float* xb = x + (size_t)b * 64 * 65536;
  const halfT* wM = wH + 12288;

  // ---------------- phase A: load x + Haar DWT -> bands -------------------
  #pragma unroll
  for (int it = 0; it < 4; ++it){
    int idx = it*512 + tid;
    int j = idx & 15, rp = (idx >> 4) & 1, c = idx >> 5;
    const float* src = xb + (size_t)c*65536 + (size_t)(4*hw + 2*rp)*256 + col0 + 4*j;
    float4 r0 = *(const float4*)src;
    float4 r1 = *(const float4*)(src + 256);
    float v0[4], v1[4];
    v0[0] = 0.5f*( r0.x + r0.y + r1.x + r1.y);
    v0[1] = 0.5f*(-r0.x - r0.y + r1.x + r1.y);
    v0[2] = 0.5f*(-r0.x + r0.y - r1.x + r1.y);
    v0[3] = 0.5f*( r0.x - r0.y - r1.x + r1.y);
    v1[0] = 0.5f*( r0.z + r0.w + r1.z + r1.w);
    v1[1] = 0.5f*(-r0.z - r0.w + r1.z + r1.w);
    v1[2] = 0.5f*(-r0.z + r0.w - r1.z + r1.w);
    v1[3] = 0.5f*( r0.z - r0.w - r1.z + r1.w);
    int base = c*64 + ((rp*32 + 2*j) ^ (((c >> 3) & 3) << 4));
    #pragma unroll
    for (int bb = 0; bb < 4; ++bb)
      *(uint32_t*)&bands[bb*4096 + base] =
          (uint32_t)f2h(v0[bb]) | ((uint32_t)f2h(v1[bb]) << 16);
  }
  __syncthreads();

  const int mrow = lane & 15, g = lane >> 4;
  const int m = lane & 31;
  const int W = wv*2 + (lane >> 5);   // window 0..15, fixed per thread
  const int A = 2*m;                  // output ch pair base
  const int np = m & 1;
  const int pxb = (wv & 3)*16 + mrow; // conv N-column
  const int wl = (pxb & 31) >> 1, qq = (pxb >> 5)*2 + (pxb & 1);
  const int ms = wv >> 2;

  // ---- LOW ----
  conv64(wH, bands, qk, 0, mrow, g, ms, pxb, wl, qq);
  __syncthreads();
  attn16(qk, m, np, W, ybuf + 0*2048, tid);   // y0 -> dead bands[0]
  __syncthreads();

  // ---- MID conv: K=128 (bands 1,2), T=384, 24 M-tiles split by ms ----
  {
    half8 bfr[4];
    #pragma unroll
    for (int ks = 0; ks < 4; ++ks){
      H8 t; int band = 1 + (ks >> 1); int cb = (ks & 1)*32 + g*8;
      #pragma unroll
      for (int k = 0; k < 8; ++k)
        t.s[k] = bands[band*4096 + (cb + k)*64 + (pxb ^ (g << 4))];
      bfr[ks] = t.v;
    }
    #pragma unroll
    for (int mi = 0; mi < 12; ++mi){
      int mt = ms*12 + mi;
      f32x4 acc = {0.f,0.f,0.f,0.f};
      #pragma unroll
      for (int ks = 0; ks < 4; ++ks){
        half8 a = *(const half8*)&wM[(mt*16 + mrow)*128 + ks*32 + g*8];
        acc = __builtin_amdgcn_mfma_f32_16x16x32_f16(a, bfr[ks], acc, 0, 0, 0);
      }
      #pragma unroll
      for (int r = 0; r < 4; ++r){
        int tl = mt*16 + g*4 + r;              // 0..383 -> G 0..95
        qk[qidx(tl >> 2, (tl & 3) >> 1, wl) + (tl & 1)*4 + qq] = f2h(acc[r]);
      }
    }
  }
  __syncthreads();

  // ---- MID attention: single pass; Q G0-31, K 32-63, V 64-95 ----
  {
    const halfT shm = (halfT)0.17677669529663687f;
    const half8 s8m = {shm,shm,shm,shm,shm,shm,shm,shm};
    H8 qa, qb;
    qa.v = (*(const half8*)&qk[qidx(m >> 1, np, W)]) * s8m;        // lh rows
    qb.v = (*(const half8*)&qk[qidx(16 + (m >> 1), np, W)]) * s8m; // hl rows
    float sm0 = 0.f, sm1 = 0.f, sm2 = 0.f, sm3 = 0.f;
    f32x4 p0 = {0.f,0.f,0.f,0.f}, p1 = {0.f,0.f,0.f,0.f};
    f32x4 p2 = {0.f,0.f,0.f,0.f}, p3 = {0.f,0.f,0.f,0.f};
    #pragma unroll
    for (int dl = 0; dl < 32; ++dl){
      H8 kg, vg;
      kg.v = *(const half8*)&qk[qidx(32 + dl, np, W)];
      vg.v = *(const half8*)&qk[qidx(64 + dl, np, W)];
      float a0 = dot4(qa.h2[0], qa.h2[1], kg.h2[0], kg.h2[1]);
      float a1 = dot4(qa.h2[2], qa.h2[3], kg.h2[2], kg.h2[3]);
      float a2 = dot4(qb.h2[0], qb.h2[1], kg.h2[0], kg.h2[1]);
      float a3 = dot4(qb.h2[2], qb.h2[3], kg.h2[2], kg.h2[3]);
      float e0 = __expf(a0), e1 = __expf(a1);
      float e2 = __expf(a2), e3 = __expf(a3);
      sm0 += e0; sm1 += e1; sm2 += e2; sm3 += e3;
      #pragma unroll
      for (int s2 = 0; s2 < 4; ++s2){
        float vlo = (float)vg.v[s2], vhi = (float)vg.v[4 + s2];
        p0[s2] += e0*vlo; p1[s2] += e1*vhi;
        p2[s2] += e2*vlo; p3[s2] += e3*vhi;
      }
    }
    float i0 = __builtin_amdgcn_rcpf(sm0), i1 = __builtin_amdgcn_rcpf(sm1);
    float i2 = __builtin_amdgcn_rcpf(sm2), i3 = __builtin_amdgcn_rcpf(sm3);
    uint32_t* y1s = ybuf + 1*2048;          // dead bands[1]
    uint32_t* y2s = ybuf + 2*2048;          // dead bands[2]
    y1s[0*512 + tid] = pk16(p0[0]*i0, p0[1]*i0);
    y1s[1*512 + tid] = pk16(p0[2]*i0, p0[3]*i0);
    y1s[2*512 + tid] = pk16(p1[0]*i1, p1[1]*i1);
    y1s[3*512 + tid] = pk16(p1[2]*i1, p1[3]*i1);
    y2s[0*512 + tid] = pk16(p2[0]*i2, p2[1]*i2);
    y2s[1*512 + tid] = pk16(p2[2]*i2, p2[3]*i2);
    y2s[2*512 + tid] = pk16(p3[0]*i3, p3[1]*i3);
    y2s[3*512 + tid] = pk16(p3[2]*i3, p3[3]*i3);
  }
  __syncthreads();

  // ---- HIGH ----
  conv64(wH, bands, qk, 3, mrow, g, ms, pxb, wl, qq);
  __syncthreads();

  // HIGH attention: y3 stays in registers (no barrier crossed before use)
  f32x4 y3l, y3h;
  {
    const halfT sh = (halfT)0.25f;
    const half8 s8 = {sh,sh,sh,sh,sh,sh,sh,sh};
    H8 qg; qg.v = (*(const half8*)&qk[qidx(m >> 1, np, W)]) * s8;
    float sum0 = 0.f, sum1 = 0.f;
    f32x4 po0 = {0.f,0.f,0.f,0.f}, po1 = {0.f,0.f,0.f,0.f};
    #pragma unroll
    for (int d = 0; d < 16; ++d){
      H8 kg, vg;
      kg.v = *(const half8*)&qk[qidx(16 + d, np, W)];
      vg.v = *(const half8*)&qk[qidx(32 + d, np, W)];
      float a0 = dot4(qg.h2[0], qg.h2[1], kg.h2[0], kg.h2[1]);
      float a1 = dot4(qg.h2[2], qg.h2[3], kg.h2[2], kg.h2[3]);
      float e0 = __expf(a0), e1 = __expf(a1);
      sum0 += e0; sum1 += e1;
      #pragma unroll
      for (int s2 = 0; s2 < 4; ++s2){
        po0[s2] += e0 * (float)vg.v[s2];
        po1[s2] += e1 * (float)vg.v[4 + s2];
      }
    }
    y3l = po0 * __builtin_amdgcn_rcpf(sum0);
    y3h = po1 * __builtin_amdgcn_rcpf(sum1);
  }

  // ---- read own y0-y2 (written by this thread; no barrier needed) ----
  float ya[3][2][4];
  #pragma unroll
  for (int p = 0; p < 3; ++p){
    #pragma unroll
    for (int w = 0; w < 4; ++w){
      uint32_t u = ybuf[p*2048 + w*512 + tid];
      ya[p][w >> 1][(w & 1)*2 + 0] = h2f((uint16_t)(u & 0xffffu));
      ya[p][w >> 1][(w & 1)*2 + 1] = h2f((uint16_t)(u >> 16));
    }
  }
  __syncthreads();   // everyone done reading smem; smem becomes ot

  // ---- iDWT in registers -> ot staging ----
  {
    const int gw = W ^ (m & 15);
    IDWT(A,     ya[0][0], ya[1][0], ya[2][0], y3l);
    IDWT(A + 1, ya[0][1], ya[1][1], ya[2][1], y3h);
  }
  __syncthreads();

  // ---- coalesced store (full-line writes) ----
  #pragma unroll
  for (int it = 0; it < 2; ++it){
    int s = it*512 + tid;
    int ch = s >> 4, row = (s >> 2) & 3, seg = s & 3;
    int sw = (ch >> 1) & 15;
    const float* rowp = &ot[ch*OT_CS + row*OT_RS];
    float4 v0 = *(const float4*)&rowp[((seg*4+0) ^ sw)*4];
    float4 v1 = *(const float4*)&rowp[((seg*4+1) ^ sw)*4];
    float4 v2 = *(const float4*)&rowp[((seg*4+2) ^ sw)*4];
    float4 v3 = *(const float4*)&rowp[((seg*4+3) ^ sw)*4];
    float* dst = out + (((size_t)b*64 + ch)*256 + (size_t)(4*hw + row))*256 + col0 + seg*16;
    ((float4*)dst)[0] = v0; ((float4*)dst)[1] = v1;
    ((float4*)dst)[2] = v2; ((float4*)dst)[3] = v3;
  }
}

// ---------------------------------------------------------------------------
extern "C" void kernel_launch(void* const* d_in, const int* in_sizes, int n_in,
                              void* d_out, int out_size, void* d_ws, size_t ws_size,
                              hipStream_t stream){
  const float* x   = (const float*)d_in[0];
  const float* wlh = (const float*)d_in[1];
  const float* wm  = (const float*)d_in[2];
  float* out = (float*)d_out;
  halfT* wH = (halfT*)d_ws;                // 61440 f16 = 122880 B

  hipLaunchKernelGGL(k_wt,    dim3(240),  dim3(256), 0, stream, wlh, wm, wH);
  hipLaunchKernelGGL(k_fused, dim3(2048), dim3(512), 0, stream, x, wH, out);
}

// Round 12
// 204.120 us; speedup vs baseline: 3.8505x; 1.0154x over previous
//
#include <hip/hip_runtime.h>
#include <stdint.h>

// ---------------------------------------------------------------------------
// Fused wavelet window-attention; packed-f16 PV accumulation; y parked in
// dead LDS band slabs (no spill).
//   Block = 512 thr: one (unit, quarter) = 4 orig rows x 64 orig cols.
//   smem 80KB = bands[4][c64][px64] f16 XOR-swz (32KB) + qk 48KB.
//   qk granule(G,np,W) 16B = channels {4G+2np, +1} x q(4 spatial).
//   After each path's conv its band slab is dead -> attention parks packed
//   half2 y there ([w*512+tid] u32, conflict-free). All 4 paths parked.
//   PV accumulates in half2 (v_pk_fma_f16) -- validated in R2-R5 runs.
// ---------------------------------------------------------------------------

typedef _Float16 halfT;
typedef __attribute__((ext_vector_type(2))) _Float16 half2T;
typedef __attribute__((ext_vector_type(8))) _Float16 half8;
typedef __attribute__((ext_vector_type(4))) float f32x4;

union H8 { half8 v; half2T h2[4]; uint16_t s[8]; };
union H2U { half2T h; uint32_t u; };

static __device__ __forceinline__ uint16_t f2h(float f){
  union { halfT h; uint16_t u; } x; x.h = (halfT)f; return x.u;
}
static __device__ __forceinline__ float h2f(uint16_t u){
  union { uint16_t u; halfT h; } x; x.u = u; return (float)x.h;
}
static __device__ __forceinline__ float dot4(half2T a0, half2T a1,
                                             half2T b0, half2T b1){
#if __has_builtin(__builtin_amdgcn_fdot2)
  return __builtin_amdgcn_fdot2(a1, b1, __builtin_amdgcn_fdot2(a0, b0, 0.f, false), false);
#else
  half2T p = a0*b0 + a1*b1;
  return (float)p.x + (float)p.y;
#endif
}
static __device__ __forceinline__ half2T pk2(float e){
#if __has_builtin(__builtin_amdgcn_cvt_pkrtz)
  union { __fp16 __attribute__((ext_vector_type(2))) p; half2T h; } c;
  c.p = __builtin_amdgcn_cvt_pkrtz(e, e);
  return c.h;
#else
  half2T r; r.x = (halfT)e; r.y = (halfT)e; return r;
#endif
}

__global__ void k_wt(const float* __restrict__ wlh, const float* __restrict__ wm,
                     halfT* __restrict__ wH){
  int i = blockIdx.x * 256 + threadIdx.x;
  if (i < 12288)      wH[i] = (halfT)wlh[i];
  else if (i < 61440) wH[i] = (halfT)wm[i - 12288];
}

#define OT_CS 276
#define OT_RS 68

static __device__ __forceinline__ int qidx(int G, int np, int W){
  return G*256 + np*128 + ((W ^ (G & 7)) << 3);
}

// low/high conv: K=64, T=192; 12 M-tiles split by ms
static __device__ __forceinline__ void conv64(const halfT* __restrict__ w,
    const uint16_t* __restrict__ bands, uint16_t* __restrict__ qk,
    int band, int mrow, int g, int ms, int pxb, int wl, int qq){
  half8 bfr[2];
  #pragma unroll
  for (int ks = 0; ks < 2; ++ks){
    H8 t; int cb = ks*32 + g*8;
    #pragma unroll
    for (int k = 0; k < 8; ++k)
      t.s[k] = bands[band*4096 + (cb + k)*64 + (pxb ^ (g << 4))];
    bfr[ks] = t.v;
  }
  #pragma unroll
  for (int mi = 0; mi < 6; ++mi){
    int mt = ms*6 + mi;
    f32x4 acc = {0.f,0.f,0.f,0.f};
    #pragma unroll
    for (int ks = 0; ks < 2; ++ks){
      half8 a = *(const half8*)&w[(mt*16 + mrow)*64 + ks*32 + g*8];
      acc = __builtin_amdgcn_mfma_f32_16x16x32_f16(a, bfr[ks], acc, 0, 0, 0);
    }
    #pragma unroll
    for (int r = 0; r < 4; ++r){
      int tl = mt*16 + g*4 + r;
      qk[qidx(tl >> 2, (tl & 3) >> 1, wl) + (tl & 1)*4 + qq] = f2h(acc[r]);
    }
  }
}

// low/high attention, packed-f16 PV -> park 4 u32 into yslab
static __device__ __forceinline__ void attn16p(const uint16_t* __restrict__ qk,
    int m, int np, int W, uint32_t* __restrict__ yslab, int tid){
  const halfT sh = (halfT)0.25f;
  const half8 s8 = {sh,sh,sh,sh,sh,sh,sh,sh};
  H8 qg; qg.v = (*(const half8*)&qk[qidx(m >> 1, np, W)]) * s8;
  float sum0 = 0.f, sum1 = 0.f;
  half2T A0 = {(halfT)0,(halfT)0}, A1 = A0, B0 = A0, B1 = A0;
  #pragma unroll
  for (int d = 0; d < 16; ++d){
    H8 kg, vg;
    kg.v = *(const half8*)&qk[qidx(16 + d, np, W)];
    vg.v = *(const half8*)&qk[qidx(32 + d, np, W)];
    float a0 = dot4(qg.h2[0], qg.h2[1], kg.h2[0], kg.h2[1]);
    float a1 = dot4(qg.h2[2], qg.h2[3], kg.h2[2], kg.h2[3]);
    float e0 = __expf(a0), e1 = __expf(a1);
    sum0 += e0; sum1 += e1;
    half2T p0 = pk2(e0), p1 = pk2(e1);
    A0 += p0*vg.h2[0]; A1 += p0*vg.h2[1];
    B0 += p1*vg.h2[2]; B1 += p1*vg.h2[3];
  }
  halfT i0 = (halfT)__builtin_amdgcn_rcpf(sum0);
  halfT i1 = (halfT)__builtin_amdgcn_rcpf(sum1);
  half2T v0 = {i0,i0}, v1 = {i1,i1};
  H2U u0, u1, u2, u3;
  u0.h = A0*v0; u1.h = A1*v0; u2.h = B0*v1; u3.h = B1*v1;
  yslab[0*512 + tid] = u0.u;
  yslab[1*512 + tid] = u1.u;
  yslab[2*512 + tid] = u2.u;
  yslab[3*512 + tid] = u3.u;
}

#define IDWT(CH, Y0, Y1, Y2, Y3) { \
  float* otc = ot + (CH)*OT_CS + gw*4; \
  _Pragma("unroll") \
  for (int rp = 0; rp < 2; ++rp){ \
    float4 top, bot; \
    _Pragma("unroll") \
    for (int cp = 0; cp < 2; ++cp){ \
      int s2 = rp*2 + cp; \
      float ll = Y0[s2], lh = Y1[s2], hl = Y2[s2], hh = Y3[s2]; \
      float va = 0.5f*(ll - lh - hl + hh); \
      float vb = 0.5f*(ll - lh + hl - hh); \
      float vc = 0.5f*(ll + lh - hl - hh); \
      float vd = 0.5f*(ll + lh + hl + hh); \
      if (cp == 0){ top.x = va; top.y = vb; bot.x = vc; bot.y = vd; } \
      else        { top.z = va; top.w = vb; bot.z = vc; bot.w = vd; } \
    } \
    *(float4*)&otc[(2*rp)*OT_RS]   = top; \
    *(float4*)&otc[(2*rp+1)*OT_RS] = bot; \
  } }

__global__ __launch_bounds__(512, 4) void k_fused(const float* __restrict__ x,
    const halfT* __restrict__ wH, float* __restrict__ out){
  __shared__ __align__(16) uint8_t smem[81920];
  uint16_t* bands = (uint16_t*)smem;                 // 32768 B
  uint16_t* qk    = (uint16_t*)(smem + 32768);       // 49152 B
  uint32_t* ybuf  = (uint32_t*)smem;                 // y slabs (dead bands)
  float*    ot    = (float*)smem;                    // reused at end

  const int tid = threadIdx.x;
  const int wv = tid >> 6, lane = tid & 63;
  const int unit = blockIdx.x >> 2, q4 = blockIdx.x & 3;
  const int b = unit >> 6, hw = unit & 63;
  const int col0 = q4 * 64;
  const float* xb = x + (size_t)b * 64 * 65536;
  const halfT* wM = wH + 12288;

  // ---------------- phase A: load x + Haar DWT -> bands -------------------
  #pragma unroll
  for (int it = 0; it < 4; ++it){
    int idx = it*512 + tid;
    int j = idx & 15, rp = (idx >> 4) & 1, c = idx >> 5;
    const float* src = xb + (size_t)c*65536 + (size_t)(4*hw + 2*rp)*256 + col0 + 4*j;
    float4 r0 = *(const float4*)src;
    float4 r1 = *(const float4*)(src + 256);
    float v0[4], v1[4];
    v0[0] = 0.5f*( r0.x + r0.y + r1.x + r1.y);
    v0[1] = 0.5f*(-r0.x - r0.y + r1.x + r1.y);
    v0[2] = 0.5f*(-r0.x + r0.y - r1.x + r1.y);
    v0[3] = 0.5f*( r0.x - r0.y - r1.x + r1.y);
    v1[0] = 0.5f*( r0.z + r0.w + r1.z + r1.w);
    v1[1] = 0.5f*(-r0.z - r0.w + r1.z + r1.w);
    v1[2] = 0.5f*(-r0.z + r0.w - r1.z + r1.w);
    v1[3] = 0.5f*( r0.z - r0.w - r1.z + r1.w);
    int base = c*64 + ((rp*32 + 2*j) ^ (((c >> 3) & 3) << 4));
    #pragma unroll
    for (int bb = 0; bb < 4; ++bb)
      *(uint32_t*)&bands[bb*4096 + base] =
          (uint32_t)f2h(v0[bb]) | ((uint32_t)f2h(v1[bb]) << 16);
  }
  __syncthreads();

  const int mrow = lane & 15, g = lane >> 4;
  const int m = lane & 31;
  const int W = wv*2 + (lane >> 5);   // window 0..15, fixed per thread
  const int A = 2*m;                  // output ch pair base
  const int np = m & 1;
  const int pxb = (wv & 3)*16 + mrow; // conv N-column
  const int wl = (pxb & 31) >> 1, qq = (pxb >> 5)*2 + (pxb & 1);
  const int ms = wv >> 2;

  // ---- LOW ----
  conv64(wH, bands, qk, 0, mrow, g, ms, pxb, wl, qq);
  __syncthreads();
  attn16p(qk, m, np, W, ybuf + 0*2048, tid);   // y0 -> dead bands[0]
  __syncthreads();

  // ---- MID conv: K=128 (bands 1,2), T=384, 24 M-tiles split by ms ----
  {
    half8 bfr[4];
    #pragma unroll
    for (int ks = 0; ks < 4; ++ks){
      H8 t; int band = 1 + (ks >> 1); int cb = (ks & 1)*32 + g*8;
      #pragma unroll
      for (int k = 0; k < 8; ++k)
        t.s[k] = bands[band*4096 + (cb + k)*64 + (pxb ^ (g << 4))];
      bfr[ks] = t.v;
    }
    #pragma unroll
    for (int mi = 0; mi < 12; ++mi){
      int mt = ms*12 + mi;
      f32x4 acc = {0.f,0.f,0.f,0.f};
      #pragma unroll
      for (int ks = 0; ks < 4; ++ks){
        half8 a = *(const half8*)&wM[(mt*16 + mrow)*128 + ks*32 + g*8];
        acc = __builtin_amdgcn_mfma_f32_16x16x32_f16(a, bfr[ks], acc, 0, 0, 0);
      }
      #pragma unroll
      for (int r = 0; r < 4; ++r){
        int tl = mt*16 + g*4 + r;              // 0..383 -> G 0..95
        qk[qidx(tl >> 2, (tl & 3) >> 1, wl) + (tl & 1)*4 + qq] = f2h(acc[r]);
      }
    }
  }
  __syncthreads();

  // ---- MID attention: single pass, packed-f16 PV; Q G0-31, K 32-63, V 64-95
  {
    const halfT shm = (halfT)0.17677669529663687f;
    const half8 s8m = {shm,shm,shm,shm,shm,shm,shm,shm};
    H8 qa, qb;
    qa.v = (*(const half8*)&qk[qidx(m >> 1, np, W)]) * s8m;        // lh rows
    qb.v = (*(const half8*)&qk[qidx(16 + (m >> 1), np, W)]) * s8m; // hl rows
    float sm0 = 0.f, sm1 = 0.f, sm2 = 0.f, sm3 = 0.f;
    half2T P0a = {(halfT)0,(halfT)0}, P0b = P0a, P1a = P0a, P1b = P0a;
    half2T P2a = P0a, P2b = P0a, P3a = P0a, P3b = P0a;
    #pragma unroll
    for (int dl = 0; dl < 32; ++dl){
      H8 kg, vg;
      kg.v = *(const half8*)&qk[qidx(32 + dl, np, W)];
      vg.v = *(const half8*)&qk[qidx(64 + dl, np, W)];
      float a0 = dot4(qa.h2[0], qa.h2[1], kg.h2[0], kg.h2[1]);
      float a1 = dot4(qa.h2[2], qa.h2[3], kg.h2[2], kg.h2[3]);
      float a2 = dot4(qb.h2[0], qb.h2[1], kg.h2[0], kg.h2[1]);
      float a3 = dot4(qb.h2[2], qb.h2[3], kg.h2[2], kg.h2[3]);
      float e0 = __expf(a0), e1 = __expf(a1);
      float e2 = __expf(a2), e3 = __expf(a3);
      sm0 += e0; sm1 += e1; sm2 += e2; sm3 += e3;
      half2T p0 = pk2(e0), p1 = pk2(e1), p2 = pk2(e2), p3 = pk2(e3);
      P0a += p0*vg.h2[0]; P0b += p0*vg.h2[1];
      P1a += p1*vg.h2[2]; P1b += p1*vg.h2[3];
      P2a += p2*vg.h2[0]; P2b += p2*vg.h2[1];
      P3a += p3*vg.h2[2]; P3b += p3*vg.h2[3];
    }
    halfT i0 = (halfT)__builtin_amdgcn_rcpf(sm0);
    halfT i1 = (halfT)__builtin_amdgcn_rcpf(sm1);
    halfT i2 = (halfT)__builtin_amdgcn_rcpf(sm2);
    halfT i3 = (halfT)__builtin_amdgcn_rcpf(sm3);
    half2T v0 = {i0,i0}, v1 = {i1,i1}, v2 = {i2,i2}, v3 = {i3,i3};
    uint32_t* y1s = ybuf + 1*2048;          // dead bands[1]
    uint32_t* y2s = ybuf + 2*2048;          // dead bands[2]
    H2U a0u, a1u, b0u, b1u, c0u, c1u, d0u, d1u;
    a0u.h = P0a*v0; a1u.h = P0b*v0; b0u.h = P1a*v1; b1u.h = P1b*v1;
    c0u.h = P2a*v2; c1u.h = P2b*v2; d0u.h = P3a*v3; d1u.h = P3b*v3;
    y1s[0*512 + tid] = a0u.u;
    y1s[1*512 + tid] = a1u.u;
    y1s[2*512 + tid] = b0u.u;
    y1s[3*512 + tid] = b1u.u;
    y2s[0*512 + tid] = c0u.u;
    y2s[1*512 + tid] = c1u.u;
    y2s[2*512 + tid] = d0u.u;
    y2s[3*512 + tid] = d1u.u;
  }
  __syncthreads();

  // ---- HIGH ----
  conv64(wH, bands, qk, 3, mrow, g, ms, pxb, wl, qq);
  __syncthreads();
  attn16p(qk, m, np, W, ybuf + 3*2048, tid);   // y3 -> dead bands[3]

  // ---- read own y0-y3 (written by this thread; no barrier needed) ----
  float ya[4][2][4];
  #pragma unroll
  for (int p = 0; p < 4; ++p){
    #pragma unroll
    for (int w = 0; w < 4; ++w){
      uint32_t u = ybuf[p*2048 + w*512 + tid];
      ya[p][w >> 1][(w & 1)*2 + 0] = h2f((uint16_t)(u & 0xffffu));
      ya[p][w >> 1][(w & 1)*2 + 1] = h2f((uint16_t)(u >> 16));
    }
  }
  __syncthreads();   // everyone done reading smem; smem becomes ot

  // ---- iDWT in registers -> ot staging ----
  {
    const int gw = W ^ (m & 15);
    IDWT(A,     ya[0][0], ya[1][0], ya[2][0], ya[3][0]);
    IDWT(A + 1, ya[0][1], ya[1][1], ya[2][1], ya[3][1]);
  }
  __syncthreads();

  // ---- coalesced store (full-line writes) ----
  #pragma unroll
  for (int it = 0; it < 2; ++it){
    int s = it*512 + tid;
    int ch = s >> 4, row = (s >> 2) & 3, seg = s & 3;
    int sw = (ch >> 1) & 15;
    const float* rowp = &ot[ch*OT_CS + row*OT_RS];
    float4 v0 = *(const float4*)&rowp[((seg*4+0) ^ sw)*4];
    float4 v1 = *(const float4*)&rowp[((seg*4+1) ^ sw)*4];
    float4 v2 = *(const float4*)&rowp[((seg*4+2) ^ sw)*4];
    float4 v3 = *(const float4*)&rowp[((seg*4+3) ^ sw)*4];
    float* dst = out + (((size_t)b*64 + ch)*256 + (size_t)(4*hw + row))*256 + col0 + seg*16;
    ((float4*)dst)[0] = v0; ((float4*)dst)[1] = v1;
    ((float4*)dst)[2] = v2; ((float4*)dst)[3] = v3;
  }
}

// ---------------------------------------------------------------------------
extern "C" void kernel_launch(void* const* d_in, const int* in_sizes, int n_in,
                              void* d_out, int out_size, void* d_ws, size_t ws_size,
                              hipStream_t stream){
  const float* x   = (const float*)d_in[0];
  const float* wlh = (const float*)d_in[1];
  const float* wm  = (const float*)d_in[2];
  float* out = (float*)d_out;
  halfT* wH = (halfT*)d_ws;                // 61440 f16 = 122880 B

  hipLaunchKernelGGL(k_wt,    dim3(240),  dim3(256), 0, stream, wlh, wm, wH);
  hipLaunchKernelGGL(k_fused, dim3(2048), dim3(512), 0, stream, x, wH, out);
}